// Round 4
// baseline (1190.578 us; speedup 1.0000x reference)
//
#include <hip/hip_runtime.h>
#include <hip/hip_fp16.h>

#define D 128
#define DP 132  // LDS row stride (floats): +4 pad; rows stay 16B-aligned.
#define TM 16   // fused layer tile: 16 nodes, ~16.5 KB LDS

typedef float f4v __attribute__((ext_vector_type(4)));

// ---------------- CSR build ----------------

__global__ void hist_kernel(const int* __restrict__ dst, int* __restrict__ deg, int E) {
    int i = blockIdx.x * blockDim.x + threadIdx.x;
    if (i < E) atomicAdd(&deg[dst[i]], 1);
}

__global__ void scan1_kernel(const int* __restrict__ deg, int* __restrict__ local_excl,
                             int* __restrict__ blocksum, int n) {
    __shared__ int tmp[1024];
    int i = blockIdx.x * 1024 + threadIdx.x;
    int v = (i < n) ? deg[i] : 0;
    tmp[threadIdx.x] = v;
    __syncthreads();
    for (int off = 1; off < 1024; off <<= 1) {
        int t = 0;
        if (threadIdx.x >= off) t = tmp[threadIdx.x - off];
        __syncthreads();
        if (threadIdx.x >= off) tmp[threadIdx.x] += t;
        __syncthreads();
    }
    int incl = tmp[threadIdx.x];
    if (i < n) local_excl[i] = incl - v;
    if (threadIdx.x == 1023) blocksum[blockIdx.x] = tmp[1023];
}

__global__ void scan2_kernel(int* __restrict__ blocksum, int nb) {
    __shared__ int tmp[1024];
    int v = (threadIdx.x < nb) ? blocksum[threadIdx.x] : 0;
    tmp[threadIdx.x] = v;
    __syncthreads();
    for (int off = 1; off < 1024; off <<= 1) {
        int t = 0;
        if (threadIdx.x >= off) t = tmp[threadIdx.x - off];
        __syncthreads();
        if (threadIdx.x >= off) tmp[threadIdx.x] += t;
        __syncthreads();
    }
    if (threadIdx.x < nb) blocksum[threadIdx.x] = tmp[threadIdx.x] - v;  // exclusive
}

__global__ void scan3_kernel(const int* __restrict__ deg, const int* __restrict__ local_excl,
                             const int* __restrict__ blocksum, int* __restrict__ row_start,
                             int* __restrict__ cursor, float* __restrict__ inv_deg,
                             int n, int n_edges) {
    int i = blockIdx.x * 1024 + threadIdx.x;
    if (i < n) {
        int rs = local_excl[i] + blocksum[blockIdx.x];
        row_start[i] = rs;
        cursor[i]    = rs;
        inv_deg[i]   = 1.0f / fmaxf((float)deg[i], 1.0f);
    }
    if (i == 0) row_start[n] = n_edges;
}

// csr[] holds BYTE offsets of the fp16 source row (src * D * 2 = src * 256).
__global__ void scatter_kernel(const int* __restrict__ src, const int* __restrict__ dst,
                               int* __restrict__ cursor, int* __restrict__ csr, int E) {
    int i = blockIdx.x * blockDim.x + threadIdx.x;
    if (i < E) {
        int d = dst[i];
        int p = atomicAdd(&cursor[d], 1);
        csr[p] = src[i] << 8;   // * 256 bytes per fp16 row
    }
}

// ---------------- weight transpose (W[l][f][k] -> Wt[l][k][f]) ----------------

__global__ void transpose_w(const float* __restrict__ Wl, const float* __restrict__ Wr,
                            float* __restrict__ Wlt, float* __restrict__ Wrt, int total) {
    int i = blockIdx.x * blockDim.x + threadIdx.x;
    if (i < total) {
        int l = i >> 14;
        int r = i & 16383;
        int f = r >> 7;
        int k = r & 127;
        int o = (l << 14) + (k << 7) + f;
        Wlt[o] = Wl[i];
        Wrt[o] = Wr[i];
    }
}

// ---------------- initial fp32 -> fp16 shadow copy ----------------

__global__ void x_to_half(const float* __restrict__ x, __half* __restrict__ xh, int total4) {
    int i = blockIdx.x * blockDim.x + threadIdx.x;   // one float4 per thread
    if (i < total4) {
        float4 v = ((const float4*)x)[i];
        __half2 h0 = __float22half2_rn(make_float2(v.x, v.y));
        __half2 h1 = __float22half2_rn(make_float2(v.z, v.w));
        uint2 u;
        u.x = *(unsigned int*)&h0;
        u.y = *(unsigned int*)&h1;
        ((uint2*)xh)[i] = u;
    }
}

// ---------------- fused SAGE layer ----------------
// Phase A (r13 change): inline-asm 8-deep gather pipeline with COUNTED
// vmcnt. r12 post-mortem: whole kernel compiled to VGPR=32, so the
// compiler serialized the gather loads (~30 lines in flight/CU vs ~2000
// possible) -- the r7-r9 "compiler sinks prefetched VMEM regs" problem.
// Remedy per guide T3/T4: asm volatile global_load_dwordx4 (saddr form) +
// s_waitcnt vmcnt(7) + sched_barrier(0) before each consume (rule #18).
// Edge indices for slots 0..31 are preloaded via 2 coalesced loads and
// distributed by __shfl (ds path), so the loop's vmcnt stream contains
// ONLY the asm row loads -> counts are exact. Consumption is select-
// masked (no divergent branches -> wave-uniform issue counts). deg>32
// tail is a plain clamped loop after the drain.
#define FMA4(ACC, W, S) ACC.x += W.x * (S); ACC.y += W.y * (S); \
                        ACC.z += W.z * (S); ACC.w += W.w * (S);

// Accumulate 8 fp16 features (one dwordx4) into sA/sB fp32 accumulators.
#define ACC8(V) { const __half2* hp_ = (const __half2*)&(V);                 \
    float2 f0_ = __half22float2(hp_[0]); float2 f1_ = __half22float2(hp_[1]);\
    float2 f2_ = __half22float2(hp_[2]); float2 f3_ = __half22float2(hp_[3]);\
    sA.x += f0_.x; sA.y += f0_.y; sA.z += f1_.x; sA.w += f1_.y;              \
    sB.x += f2_.x; sB.y += f2_.y; sB.z += f3_.x; sB.w += f3_.y; }

// asm gather pipeline primitives
#define GLD(DST, VOFF) asm volatile("global_load_dwordx4 %0, %1, %2" \
    : "=v"(DST) : "v"(VOFF), "s"(xh_in))
#define WAITV(N) do { asm volatile("s_waitcnt vmcnt(" #N ")" ::: "memory"); \
    __builtin_amdgcn_sched_barrier(0); } while (0)
// select slot's row byte-offset: preloaded idxA (slots 0..15) / idxB (16..31)
#define ISS(RJ, SLOT) do { int s_ = (SLOT);                                  \
    int v_ = (s_ & 16) ? idxB : idxA;                                        \
    int i_ = __shfl(v_, (tid & 48) | (s_ & 15));                             \
    int a_ = i_ + laneoff; GLD(RJ, a_); } while (0)
// masked consume of slot s from pipeline reg RJ
#define CONS(RJ, SLOT) do { f4v vv_ = ((SLOT) < deg) ? (RJ) : vz; ACC8(vv_) } while (0)

__global__ __launch_bounds__(256, 6)
void sage_layer(const float* __restrict__ xin,
                const __half* __restrict__ xh_in,
                float* __restrict__ xout,
                __half* __restrict__ xh_out,
                const int* __restrict__ row_start, const int* __restrict__ csr,
                const float* __restrict__ inv_deg,
                const float* __restrict__ Wlt, const float* __restrict__ Wrt,
                const float* __restrict__ bl, int n_nodes) {
    __shared__ __align__(16) float A[TM][DP];
    __shared__ __align__(16) float X[TM][DP];
    int block0 = blockIdx.x * TM;
    int tid = threadIdx.x;

    // X-tile fill: 512 float4s, 2 per thread, nt loads (stream, read once).
    {
        for (int idx = tid; idx < TM * 32; idx += 256) {
            int row = idx >> 5, c4 = idx & 31;
            int nn = block0 + row;
            f4v v = {0.f, 0.f, 0.f, 0.f};
            if (nn < n_nodes)
                v = __builtin_nontemporal_load((const f4v*)(xin + (size_t)nn * D) + c4);
            *((f4v*)X[row] + c4) = v;
        }
    }

    // Phase A: group g (16 lanes) owns node block0+g.
    {
        int g   = tid >> 4;       // 0..15
        int sub = tid & 15;
        int n = block0 + g;
        int laneoff = sub * 16;   // 16B per lane within 256B row
        float4 sA = {0, 0, 0, 0}, sB = {0, 0, 0, 0};
        f4v vz = {0.f, 0.f, 0.f, 0.f};
        float idg = 1.f;
        int e0 = 0, e1 = 0;
        if (n < n_nodes) {
            e0 = row_start[n];
            e1 = row_start[n + 1];
            idg = inv_deg[n];
        }
        int deg  = e1 - e0;
        int last = e1 - 1;
        int lc   = max(last, 0);
        // Preload up to 32 edge byte-offsets (always reads a valid csr
        // entry -> value is always a legit row offset; & mask is belt-and-
        // braces to keep any address inside the workspace, 256B-aligned).
        int idxA = csr[min(e0 + sub,      lc)] & 0x01FFFF00;
        int idxB = csr[min(e0 + 16 + sub, lc)] & 0x01FFFF00;
        // wave-uniform slot count = max deg over the wave's 4 groups
        int dmax = deg;
        dmax = max(dmax, __shfl_xor(dmax, 16));
        dmax = max(dmax, __shfl_xor(dmax, 32));
        int Wmain = min(dmax, 32);

        if (dmax > 0) {
            f4v r0, r1, r2, r3, r4, r5, r6, r7;
            // clean vmcnt state: everything older is drained once here,
            // so the counted waits below track ONLY the asm loads.
            asm volatile("s_waitcnt vmcnt(0)" ::: "memory");
            __builtin_amdgcn_sched_barrier(0);
            // prologue: 8 loads in flight (clamped slots are harmless)
            ISS(r0, 0); ISS(r1, 1); ISS(r2, 2); ISS(r3, 3);
            ISS(r4, 4); ISS(r5, 5); ISS(r6, 6); ISS(r7, 7);
            int w = 0;
            while (w + 8 < Wmain) {   // wave-uniform trip count
                WAITV(7); CONS(r0, w + 0); ISS(r0, w + 8);
                WAITV(7); CONS(r1, w + 1); ISS(r1, w + 9);
                WAITV(7); CONS(r2, w + 2); ISS(r2, w + 10);
                WAITV(7); CONS(r3, w + 3); ISS(r3, w + 11);
                WAITV(7); CONS(r4, w + 4); ISS(r4, w + 12);
                WAITV(7); CONS(r5, w + 5); ISS(r5, w + 13);
                WAITV(7); CONS(r6, w + 6); ISS(r6, w + 14);
                WAITV(7); CONS(r7, w + 7); ISS(r7, w + 15);
                w += 8;
            }
            // epilogue: drain the 8 in flight
            WAITV(7); CONS(r0, w + 0);
            WAITV(6); CONS(r1, w + 1);
            WAITV(5); CONS(r2, w + 2);
            WAITV(4); CONS(r3, w + 3);
            WAITV(3); CONS(r4, w + 4);
            WAITV(2); CONS(r5, w + 5);
            WAITV(1); CONS(r6, w + 6);
            WAITV(0); CONS(r7, w + 7);
        }

        // tail: rare deg > 32 (plain clamped 4-deep loop, vmcnt stream is
        // empty here so compiler-emitted waits are independent).
        int e = e0 + 32;
        if (e < e1) {
            const char* hbase = (const char*)xh_in;
            int i0 = csr[min(e,     last)];
            int i1 = csr[min(e + 1, last)];
            int i2 = csr[min(e + 2, last)];
            int i3 = csr[min(e + 3, last)];
            while (1) {
                float4 v0 = *(const float4*)(hbase + (size_t)(i0 + laneoff));
                float4 v1 = *(const float4*)(hbase + (size_t)(i1 + laneoff));
                float4 v2 = *(const float4*)(hbase + (size_t)(i2 + laneoff));
                float4 v3 = *(const float4*)(hbase + (size_t)(i3 + laneoff));
                int en = e + 4;
                bool more = en < e1;
                int p0, p1, p2, p3;
                if (more) {
                    p0 = csr[min(en,     last)];
                    p1 = csr[min(en + 1, last)];
                    p2 = csr[min(en + 2, last)];
                    p3 = csr[min(en + 3, last)];
                }
                ACC8(v0)
                if (e + 1 <= last) ACC8(v1)
                if (e + 2 <= last) ACC8(v2)
                if (e + 3 <= last) ACC8(v3)
                if (!more) break;
                e = en;
                i0 = p0; i1 = p1; i2 = p2; i3 = p3;
            }
        }

        sA.x *= idg; sA.y *= idg; sA.z *= idg; sA.w *= idg;
        sB.x *= idg; sB.y *= idg; sB.z *= idg; sB.w *= idg;
        ((float4*)A[g])[sub * 2]     = sA;
        ((float4*)A[g])[sub * 2 + 1] = sB;
    }
    __syncthreads();

    // Phase B: wave w owns feature float4-columns [w*8, w*8+8) for all 16
    // nodes. Thread = 8 features x 2 nodes, k-step 4, chained fmacs.
    {
        int lane = tid & 63;
        int w    = tid >> 6;
        int c8   = lane & 7;        // float4 col within wave slice
        int tn   = lane >> 3;       // 0..7
        int cols4 = w * 8 + c8;     // global float4 col 0..31
        int j0 = tn * 2, j1 = j0 + 1;
        const float4* wlp = (const float4*)Wlt + cols4;   // row k at wlp[k*32]
        const float4* wrp = (const float4*)Wrt + cols4;
        float4 bv = ((const float4*)bl)[cols4];
        float4 acc0 = bv, acc1 = bv;
        const float* Arow0 = A[j0];
        const float* Arow1 = A[j1];
        const float* Xrow0 = X[j0];
        const float* Xrow1 = X[j1];

        for (int k = 0; k < D; k += 4) {
            float4 wl0 = wlp[(k + 0) * 32];
            float4 wl1 = wlp[(k + 1) * 32];
            float4 wl2 = wlp[(k + 2) * 32];
            float4 wl3 = wlp[(k + 3) * 32];
            float4 wr0 = wrp[(k + 0) * 32];
            float4 wr1 = wrp[(k + 1) * 32];
            float4 wr2 = wrp[(k + 2) * 32];
            float4 wr3 = wrp[(k + 3) * 32];
            float4 a0 = *(const float4*)&Arow0[k];
            float4 a1 = *(const float4*)&Arow1[k];
            float4 x0 = *(const float4*)&Xrow0[k];
            float4 x1 = *(const float4*)&Xrow1[k];

            FMA4(acc0, wl0, a0.x) FMA4(acc0, wl1, a0.y)
            FMA4(acc0, wl2, a0.z) FMA4(acc0, wl3, a0.w)
            FMA4(acc0, wr0, x0.x) FMA4(acc0, wr1, x0.y)
            FMA4(acc0, wr2, x0.z) FMA4(acc0, wr3, x0.w)
            FMA4(acc1, wl0, a1.x) FMA4(acc1, wl1, a1.y)
            FMA4(acc1, wl2, a1.z) FMA4(acc1, wl3, a1.w)
            FMA4(acc1, wr0, x1.x) FMA4(acc1, wr1, x1.y)
            FMA4(acc1, wr2, x1.z) FMA4(acc1, wr3, x1.w)
        }

        int n0 = block0 + j0, n1 = block0 + j1;
        if (n0 < n_nodes) {
            f4v r;
            r.x = fmaxf(acc0.x, 0.f); r.y = fmaxf(acc0.y, 0.f);
            r.z = fmaxf(acc0.z, 0.f); r.w = fmaxf(acc0.w, 0.f);
            __builtin_nontemporal_store(r, (f4v*)xout + (size_t)n0 * 32 + cols4);
            __half2 h0 = __float22half2_rn(make_float2(r.x, r.y));
            __half2 h1 = __float22half2_rn(make_float2(r.z, r.w));
            uint2 u;
            u.x = *(unsigned int*)&h0;
            u.y = *(unsigned int*)&h1;
            ((uint2*)xh_out)[(size_t)n0 * 32 + cols4] = u;
        }
        if (n1 < n_nodes) {
            f4v r;
            r.x = fmaxf(acc1.x, 0.f); r.y = fmaxf(acc1.y, 0.f);
            r.z = fmaxf(acc1.z, 0.f); r.w = fmaxf(acc1.w, 0.f);
            __builtin_nontemporal_store(r, (f4v*)xout + (size_t)n1 * 32 + cols4);
            __half2 h0 = __float22half2_rn(make_float2(r.x, r.y));
            __half2 h1 = __float22half2_rn(make_float2(r.z, r.w));
            uint2 u;
            u.x = *(unsigned int*)&h0;
            u.y = *(unsigned int*)&h1;
            ((uint2*)xh_out)[(size_t)n1 * 32 + cols4] = u;
        }
    }
}

extern "C" void kernel_launch(void* const* d_in, const int* in_sizes, int n_in,
                              void* d_out, int out_size, void* d_ws, size_t ws_size,
                              hipStream_t stream) {
    const float* x  = (const float*)d_in[0];
    const int*  edge = (const int*)d_in[1];
    const float* Wl = (const float*)d_in[2];
    const float* bl = (const float*)d_in[3];
    const float* Wr = (const float*)d_in[4];

    int N = in_sizes[0] / D;
    int E = in_sizes[1] / 2;
    int L = in_sizes[3] / D;
    const int* srcp = edge;
    const int* dstp = edge + E;

    char* w = (char*)d_ws;
    auto alloc = [&](size_t bytes) {
        char* p = w;
        w += (bytes + 255) & ~(size_t)255;
        return p;
    };
    int*   deg       = (int*)alloc((size_t)N * 4);
    int*   local_ex  = (int*)alloc((size_t)N * 4);
    int*   row_start = (int*)alloc((size_t)(N + 1) * 4);
    int*   cursor    = (int*)alloc((size_t)N * 4);
    int*   csr       = (int*)alloc((size_t)E * 4);
    float* invdeg    = (float*)alloc((size_t)N * 4);
    int*   blocksum  = (int*)alloc((size_t)1024 * 4);
    float* wlt       = (float*)alloc((size_t)L * D * D * 4);
    float* wrt       = (float*)alloc((size_t)L * D * D * 4);
    float* buf0      = (float*)alloc((size_t)N * D * 4);
    __half* xh0      = (__half*)alloc((size_t)N * D * 2);
    __half* xh1      = (__half*)alloc((size_t)N * D * 2);

    int nb1 = (N + 1023) / 1024;
    hipMemsetAsync(deg, 0, (size_t)N * 4, stream);
    hist_kernel<<<(E + 255) / 256, 256, 0, stream>>>(dstp, deg, E);
    scan1_kernel<<<nb1, 1024, 0, stream>>>(deg, local_ex, blocksum, N);
    scan2_kernel<<<1, 1024, 0, stream>>>(blocksum, nb1);
    scan3_kernel<<<nb1, 1024, 0, stream>>>(deg, local_ex, blocksum, row_start,
                                           cursor, invdeg, N, E);
    scatter_kernel<<<(E + 255) / 256, 256, 0, stream>>>(srcp, dstp, cursor, csr, E);
    int tw = L * D * D;
    transpose_w<<<(tw + 255) / 256, 256, 0, stream>>>(Wl, Wr, wlt, wrt, tw);
    int t4 = N * (D / 4);
    x_to_half<<<(t4 + 255) / 256, 256, 0, stream>>>(x, xh0, t4);

    float* out = (float*)d_out;
    const float* cur = x;
    int nbl = (N + TM - 1) / TM;
    for (int l = 0; l < L; ++l) {
        float* o = (l & 1) ? out : buf0;
        if (l == L - 1) o = out;
        __half* hin  = (l & 1) ? xh1 : xh0;
        __half* hout = (l & 1) ? xh0 : xh1;
        sage_layer<<<nbl, 256, 0, stream>>>(cur, hin, o, hout, row_start, csr, invdeg,
                                            wlt + (size_t)l * D * D,
                                            wrt + (size_t)l * D * D,
                                            bl + (size_t)l * D, N);
        cur = o;
    }
}

// Round 5
// 1144.147 us; speedup vs baseline: 1.0406x; 1.0406x over previous
//
#include <hip/hip_runtime.h>
#include <hip/hip_fp16.h>

#define D 128
#define DP 132  // LDS row stride (floats): +4 pad; rows stay 16B-aligned.
#define TM 16   // fused layer tile: 16 nodes, ~16.5 KB LDS -> 8 blocks/CU

typedef float f4v __attribute__((ext_vector_type(4)));
typedef float f2v __attribute__((ext_vector_type(2)));

#define Q8_SCALE 16.0f      // fp8 storage scale: |act|*16 << 448 (e4m3 max)
#define Q8_INV   0.0625f

// ---------------- CSR build ----------------

__global__ void hist_kernel(const int* __restrict__ dst, int* __restrict__ deg, int E) {
    int i = blockIdx.x * blockDim.x + threadIdx.x;
    if (i < E) atomicAdd(&deg[dst[i]], 1);
}

__global__ void scan1_kernel(const int* __restrict__ deg, int* __restrict__ local_excl,
                             int* __restrict__ blocksum, int n) {
    __shared__ int tmp[1024];
    int i = blockIdx.x * 1024 + threadIdx.x;
    int v = (i < n) ? deg[i] : 0;
    tmp[threadIdx.x] = v;
    __syncthreads();
    for (int off = 1; off < 1024; off <<= 1) {
        int t = 0;
        if (threadIdx.x >= off) t = tmp[threadIdx.x - off];
        __syncthreads();
        if (threadIdx.x >= off) tmp[threadIdx.x] += t;
        __syncthreads();
    }
    int incl = tmp[threadIdx.x];
    if (i < n) local_excl[i] = incl - v;
    if (threadIdx.x == 1023) blocksum[blockIdx.x] = tmp[1023];
}

__global__ void scan2_kernel(int* __restrict__ blocksum, int nb) {
    __shared__ int tmp[1024];
    int v = (threadIdx.x < nb) ? blocksum[threadIdx.x] : 0;
    tmp[threadIdx.x] = v;
    __syncthreads();
    for (int off = 1; off < 1024; off <<= 1) {
        int t = 0;
        if (threadIdx.x >= off) t = tmp[threadIdx.x - off];
        __syncthreads();
        if (threadIdx.x >= off) tmp[threadIdx.x] += t;
        __syncthreads();
    }
    if (threadIdx.x < nb) blocksum[threadIdx.x] = tmp[threadIdx.x] - v;  // exclusive
}

__global__ void scan3_kernel(const int* __restrict__ deg, const int* __restrict__ local_excl,
                             const int* __restrict__ blocksum, int* __restrict__ row_start,
                             int* __restrict__ cursor, float* __restrict__ inv_deg,
                             int n, int n_edges) {
    int i = blockIdx.x * 1024 + threadIdx.x;
    if (i < n) {
        int rs = local_excl[i] + blocksum[blockIdx.x];
        row_start[i] = rs;
        cursor[i]    = rs;
        inv_deg[i]   = 1.0f / fmaxf((float)deg[i], 1.0f);
    }
    if (i == 0) row_start[n] = n_edges;
}

// csr[] holds BYTE offsets of the fp8 source row (src * D = src * 128).
// fp16 consumers shift left by 1 (row = 256B).
__global__ void scatter_kernel(const int* __restrict__ src, const int* __restrict__ dst,
                               int* __restrict__ cursor, int* __restrict__ csr, int E) {
    int i = blockIdx.x * blockDim.x + threadIdx.x;
    if (i < E) {
        int d = dst[i];
        int p = atomicAdd(&cursor[d], 1);
        csr[p] = src[i] << 7;   // * 128 bytes per fp8 row
    }
}

// ---------------- weight transpose (W[l][f][k] -> Wt[l][k][f]) ----------------

__global__ void transpose_w(const float* __restrict__ Wl, const float* __restrict__ Wr,
                            float* __restrict__ Wlt, float* __restrict__ Wrt, int total) {
    int i = blockIdx.x * blockDim.x + threadIdx.x;
    if (i < total) {
        int l = i >> 14;
        int r = i & 16383;
        int f = r >> 7;
        int k = r & 127;
        int o = (l << 14) + (k << 7) + f;
        Wlt[o] = Wl[i];
        Wrt[o] = Wr[i];
    }
}

// ---------------- initial fp32 -> fp8(e4m3, x16) shadow copy ----------------

__global__ void x_to_fp8(const float* __restrict__ x, unsigned* __restrict__ xq, int total4) {
    int i = blockIdx.x * blockDim.x + threadIdx.x;   // one float4 -> one u32
    if (i < total4) {
        float4 v = ((const float4*)x)[i];
        unsigned u = 0;
        u = __builtin_amdgcn_cvt_pk_fp8_f32(v.x * Q8_SCALE, v.y * Q8_SCALE, u, false);
        u = __builtin_amdgcn_cvt_pk_fp8_f32(v.z * Q8_SCALE, v.w * Q8_SCALE, u, true);
        xq[i] = u;
    }
}

// ---------------- fused SAGE layer ----------------
// r14: fp8(e4m3) gather for layers 0..2, fp16 for layer 3 (precision hedge:
// last-layer agg error is undamped by later mixing). r13 post-mortem: forced
// 8-deep asm pipeline left the line-service rate pinned at ~0.043 lines/cy/CU
// -> HW caps outstanding gather lines (~30/CU, MSHR-class). Under cap,
// time = lines x latency / cap: the only levers are LINES (fp8 halves:
// 256B row -> 128B = 2 lines/edge) and LATENCY (12.8MB gather set -> much
// higher L2 hit fraction). Gather structure = r12 (plain 4-deep, best so
// far); no launch_bounds (r13's 6 cost 80->61% occupancy).
// INFMT/OUTFMT: 0=fp8, 1=fp16, 2=none(skip shadow write).
#define FMA4(ACC, W, S) ACC.x += W.x * (S); ACC.y += W.y * (S); \
                        ACC.z += W.z * (S); ACC.w += W.w * (S);

// fp16: accumulate 8 features (one dwordx4) into sA/sB.
#define ACC8(V) { const __half2* hp_ = (const __half2*)&(V);                 \
    float2 f0_ = __half22float2(hp_[0]); float2 f1_ = __half22float2(hp_[1]);\
    float2 f2_ = __half22float2(hp_[2]); float2 f3_ = __half22float2(hp_[3]);\
    sA.x += f0_.x; sA.y += f0_.y; sA.z += f1_.x; sA.w += f1_.y;              \
    sB.x += f2_.x; sB.y += f2_.y; sB.z += f3_.x; sB.w += f3_.y; }

// fp8: accumulate 8 features (one dwordx2) into sA/sB via HW cvt.
#define ACC8Q(V) {                                                           \
    f2v q0_ = __builtin_amdgcn_cvt_pk_f32_fp8((int)(V).x, false);            \
    f2v q1_ = __builtin_amdgcn_cvt_pk_f32_fp8((int)(V).x, true);             \
    f2v q2_ = __builtin_amdgcn_cvt_pk_f32_fp8((int)(V).y, false);            \
    f2v q3_ = __builtin_amdgcn_cvt_pk_f32_fp8((int)(V).y, true);             \
    sA.x += q0_.x; sA.y += q0_.y; sA.z += q1_.x; sA.w += q1_.y;              \
    sB.x += q2_.x; sB.y += q2_.y; sB.z += q3_.x; sB.w += q3_.y; }

template<int INFMT, int OUTFMT>
__global__ void sage_layer(const float* __restrict__ xin,
                           const void* __restrict__ xq_in,
                           float* __restrict__ xout,
                           void* __restrict__ xq_out,
                           const int* __restrict__ row_start, const int* __restrict__ csr,
                           const float* __restrict__ inv_deg,
                           const float* __restrict__ Wlt, const float* __restrict__ Wrt,
                           const float* __restrict__ bl, int n_nodes) {
    __shared__ __align__(16) float A[TM][DP];
    __shared__ __align__(16) float X[TM][DP];
    int block0 = blockIdx.x * TM;
    int tid = threadIdx.x;

    // X-tile fill: 512 float4s, 2 per thread, nt loads (stream, read once).
    {
        for (int idx = tid; idx < TM * 32; idx += 256) {
            int row = idx >> 5, c4 = idx & 31;
            int nn = block0 + row;
            f4v v = {0.f, 0.f, 0.f, 0.f};
            if (nn < n_nodes)
                v = __builtin_nontemporal_load((const f4v*)(xin + (size_t)nn * D) + c4);
            *((f4v*)X[row] + c4) = v;
        }
    }

    // Phase A: group g (16 lanes) owns node block0+g; 4-deep edge pipeline
    // with csr-index prefetch (r12 structure).
    {
        int g   = tid >> 4;       // 0..15
        int sub = tid & 15;
        int n = block0 + g;
        float4 sA = {0, 0, 0, 0}, sB = {0, 0, 0, 0};
        float idg = 1.f;
        int e0 = 0, e1 = 0;
        if (n < n_nodes) {
            e0 = row_start[n];
            e1 = row_start[n + 1];
            idg = inv_deg[n];
        }
        int e = e0;
        if (e < e1) {
            int last = e1 - 1;
            if constexpr (INFMT == 0) {
                const char* qbase = (const char*)xq_in;
                int laneoff = sub * 8;    // 8B per lane within 128B fp8 row
                int i0 = csr[min(e,     last)];
                int i1 = csr[min(e + 1, last)];
                int i2 = csr[min(e + 2, last)];
                int i3 = csr[min(e + 3, last)];
                while (1) {
                    uint2 v0 = *(const uint2*)(qbase + (size_t)(i0 + laneoff));
                    uint2 v1 = *(const uint2*)(qbase + (size_t)(i1 + laneoff));
                    uint2 v2 = *(const uint2*)(qbase + (size_t)(i2 + laneoff));
                    uint2 v3 = *(const uint2*)(qbase + (size_t)(i3 + laneoff));
                    int en = e + 4;
                    bool more = en < e1;
                    int p0, p1, p2, p3;
                    if (more) {
                        p0 = csr[min(en,     last)];
                        p1 = csr[min(en + 1, last)];
                        p2 = csr[min(en + 2, last)];
                        p3 = csr[min(en + 3, last)];
                    }
                    ACC8Q(v0)
                    if (e + 1 <= last) ACC8Q(v1)
                    if (e + 2 <= last) ACC8Q(v2)
                    if (e + 3 <= last) ACC8Q(v3)
                    if (!more) break;
                    e = en;
                    i0 = p0; i1 = p1; i2 = p2; i3 = p3;
                }
            } else {
                const char* hbase = (const char*)xq_in;
                int laneoff = sub * 16;   // 16B per lane within 256B fp16 row
                int i0 = csr[min(e,     last)] << 1;
                int i1 = csr[min(e + 1, last)] << 1;
                int i2 = csr[min(e + 2, last)] << 1;
                int i3 = csr[min(e + 3, last)] << 1;
                while (1) {
                    float4 v0 = *(const float4*)(hbase + (size_t)(i0 + laneoff));
                    float4 v1 = *(const float4*)(hbase + (size_t)(i1 + laneoff));
                    float4 v2 = *(const float4*)(hbase + (size_t)(i2 + laneoff));
                    float4 v3 = *(const float4*)(hbase + (size_t)(i3 + laneoff));
                    int en = e + 4;
                    bool more = en < e1;
                    int p0, p1, p2, p3;
                    if (more) {
                        p0 = csr[min(en,     last)] << 1;
                        p1 = csr[min(en + 1, last)] << 1;
                        p2 = csr[min(en + 2, last)] << 1;
                        p3 = csr[min(en + 3, last)] << 1;
                    }
                    ACC8(v0)
                    if (e + 1 <= last) ACC8(v1)
                    if (e + 2 <= last) ACC8(v2)
                    if (e + 3 <= last) ACC8(v3)
                    if (!more) break;
                    e = en;
                    i0 = p0; i1 = p1; i2 = p2; i3 = p3;
                }
            }
        }
        float sc = (INFMT == 0) ? idg * Q8_INV : idg;   // undo storage scale
        sA.x *= sc; sA.y *= sc; sA.z *= sc; sA.w *= sc;
        sB.x *= sc; sB.y *= sc; sB.z *= sc; sB.w *= sc;
        ((float4*)A[g])[sub * 2]     = sA;
        ((float4*)A[g])[sub * 2 + 1] = sB;
    }
    __syncthreads();

    // Phase B: wave w owns feature float4-columns [w*8, w*8+8) for all 16
    // nodes. Thread = 8 features x 2 nodes, k-step 4, chained fmacs.
    {
        int lane = tid & 63;
        int w    = tid >> 6;
        int c8   = lane & 7;        // float4 col within wave slice
        int tn   = lane >> 3;       // 0..7
        int cols4 = w * 8 + c8;     // global float4 col 0..31
        int j0 = tn * 2, j1 = j0 + 1;
        const float4* wlp = (const float4*)Wlt + cols4;   // row k at wlp[k*32]
        const float4* wrp = (const float4*)Wrt + cols4;
        float4 bv = ((const float4*)bl)[cols4];
        float4 acc0 = bv, acc1 = bv;
        const float* Arow0 = A[j0];
        const float* Arow1 = A[j1];
        const float* Xrow0 = X[j0];
        const float* Xrow1 = X[j1];

        for (int k = 0; k < D; k += 4) {
            float4 wl0 = wlp[(k + 0) * 32];
            float4 wl1 = wlp[(k + 1) * 32];
            float4 wl2 = wlp[(k + 2) * 32];
            float4 wl3 = wlp[(k + 3) * 32];
            float4 wr0 = wrp[(k + 0) * 32];
            float4 wr1 = wrp[(k + 1) * 32];
            float4 wr2 = wrp[(k + 2) * 32];
            float4 wr3 = wrp[(k + 3) * 32];
            float4 a0 = *(const float4*)&Arow0[k];
            float4 a1 = *(const float4*)&Arow1[k];
            float4 x0 = *(const float4*)&Xrow0[k];
            float4 x1 = *(const float4*)&Xrow1[k];

            FMA4(acc0, wl0, a0.x) FMA4(acc0, wl1, a0.y)
            FMA4(acc0, wl2, a0.z) FMA4(acc0, wl3, a0.w)
            FMA4(acc0, wr0, x0.x) FMA4(acc0, wr1, x0.y)
            FMA4(acc0, wr2, x0.z) FMA4(acc0, wr3, x0.w)
            FMA4(acc1, wl0, a1.x) FMA4(acc1, wl1, a1.y)
            FMA4(acc1, wl2, a1.z) FMA4(acc1, wl3, a1.w)
            FMA4(acc1, wr0, x1.x) FMA4(acc1, wr1, x1.y)
            FMA4(acc1, wr2, x1.z) FMA4(acc1, wr3, x1.w)
        }

        int n0 = block0 + j0, n1 = block0 + j1;
        #pragma unroll
        for (int q = 0; q < 2; ++q) {
            int nn = q ? n1 : n0;
            float4 acc = q ? acc1 : acc0;
            if (nn < n_nodes) {
                f4v r;
                r.x = fmaxf(acc.x, 0.f); r.y = fmaxf(acc.y, 0.f);
                r.z = fmaxf(acc.z, 0.f); r.w = fmaxf(acc.w, 0.f);
                __builtin_nontemporal_store(r, (f4v*)xout + (size_t)nn * 32 + cols4);
                if constexpr (OUTFMT == 0) {
                    unsigned u = 0;
                    u = __builtin_amdgcn_cvt_pk_fp8_f32(r.x * Q8_SCALE, r.y * Q8_SCALE, u, false);
                    u = __builtin_amdgcn_cvt_pk_fp8_f32(r.z * Q8_SCALE, r.w * Q8_SCALE, u, true);
                    ((unsigned*)xq_out)[(size_t)nn * 32 + cols4] = u;
                } else if constexpr (OUTFMT == 1) {
                    __half2 h0 = __float22half2_rn(make_float2(r.x, r.y));
                    __half2 h1 = __float22half2_rn(make_float2(r.z, r.w));
                    uint2 u;
                    u.x = *(unsigned int*)&h0;
                    u.y = *(unsigned int*)&h1;
                    ((uint2*)xq_out)[(size_t)nn * 32 + cols4] = u;
                }
            }
        }
    }
}

extern "C" void kernel_launch(void* const* d_in, const int* in_sizes, int n_in,
                              void* d_out, int out_size, void* d_ws, size_t ws_size,
                              hipStream_t stream) {
    const float* x  = (const float*)d_in[0];
    const int*  edge = (const int*)d_in[1];
    const float* Wl = (const float*)d_in[2];
    const float* bl = (const float*)d_in[3];
    const float* Wr = (const float*)d_in[4];

    int N = in_sizes[0] / D;
    int E = in_sizes[1] / 2;
    int L = in_sizes[3] / D;   // 4
    const int* srcp = edge;
    const int* dstp = edge + E;

    char* w = (char*)d_ws;
    auto alloc = [&](size_t bytes) {
        char* p = w;
        w += (bytes + 255) & ~(size_t)255;
        return p;
    };
    int*   deg       = (int*)alloc((size_t)N * 4);
    int*   local_ex  = (int*)alloc((size_t)N * 4);
    int*   row_start = (int*)alloc((size_t)(N + 1) * 4);
    int*   cursor    = (int*)alloc((size_t)N * 4);
    int*   csr       = (int*)alloc((size_t)E * 4);
    float* invdeg    = (float*)alloc((size_t)N * 4);
    int*   blocksum  = (int*)alloc((size_t)1024 * 4);
    float* wlt       = (float*)alloc((size_t)L * D * D * 4);
    float* wrt       = (float*)alloc((size_t)L * D * D * 4);
    float* buf0      = (float*)alloc((size_t)N * D * 4);
    unsigned* q0     = (unsigned*)alloc((size_t)N * D);      // fp8 rows
    void*  q1        = (void*)alloc((size_t)N * D * 2);      // fp8 or fp16 rows

    int nb1 = (N + 1023) / 1024;
    hipMemsetAsync(deg, 0, (size_t)N * 4, stream);
    hist_kernel<<<(E + 255) / 256, 256, 0, stream>>>(dstp, deg, E);
    scan1_kernel<<<nb1, 1024, 0, stream>>>(deg, local_ex, blocksum, N);
    scan2_kernel<<<1, 1024, 0, stream>>>(blocksum, nb1);
    scan3_kernel<<<nb1, 1024, 0, stream>>>(deg, local_ex, blocksum, row_start,
                                           cursor, invdeg, N, E);
    scatter_kernel<<<(E + 255) / 256, 256, 0, stream>>>(srcp, dstp, cursor, csr, E);
    int tw = L * D * D;
    transpose_w<<<(tw + 255) / 256, 256, 0, stream>>>(Wl, Wr, wlt, wrt, tw);
    int t4 = N * (D / 4);
    x_to_fp8<<<(t4 + 255) / 256, 256, 0, stream>>>(x, q0, t4);

    float* out = (float*)d_out;
    int nbl = (N + TM - 1) / TM;
    size_t DD = (size_t)D * D;

    // l0: gather fp8(x) -> write fp8          fp32: x    -> buf0
    sage_layer<0, 0><<<nbl, 256, 0, stream>>>(x, q0, buf0, q1, row_start, csr, invdeg,
                                              wlt + 0 * DD, wrt + 0 * DD, bl + 0 * D, N);
    // l1: gather fp8 -> write fp8             fp32: buf0 -> out
    sage_layer<0, 0><<<nbl, 256, 0, stream>>>(buf0, q1, out, q0, row_start, csr, invdeg,
                                              wlt + 1 * DD, wrt + 1 * DD, bl + 1 * D, N);
    // l2: gather fp8 -> write FP16 (hedge)    fp32: out  -> buf0
    sage_layer<0, 1><<<nbl, 256, 0, stream>>>(out, q0, buf0, q1, row_start, csr, invdeg,
                                              wlt + 2 * DD, wrt + 2 * DD, bl + 2 * D, N);
    // l3: gather fp16 -> no shadow write      fp32: buf0 -> out (final)
    sage_layer<1, 2><<<nbl, 256, 0, stream>>>(buf0, q1, out, nullptr, row_start, csr, invdeg,
                                              wlt + 3 * DD, wrt + 3 * DD, bl + 3 * D, N);
}

// Round 6
// 827.679 us; speedup vs baseline: 1.4385x; 1.3824x over previous
//
#include <hip/hip_runtime.h>
#include <hip/hip_fp16.h>

#define D 128
#define DP 132  // LDS row stride (floats): 528B row stays 16B-aligned.
#define TM 32   // r15: 32 nodes/block, 256 thr -> weight-load instrs/node halve

typedef float f4v __attribute__((ext_vector_type(4)));
typedef float f2v __attribute__((ext_vector_type(2)));

#define Q8_SCALE 16.0f      // fp8 storage scale: |act|*16 << 448 (e4m3 max)
#define Q8_INV   0.0625f

// ---------------- CSR build ----------------

__global__ void hist_kernel(const int* __restrict__ dst, int* __restrict__ deg, int E) {
    int i = blockIdx.x * blockDim.x + threadIdx.x;
    if (i < E) atomicAdd(&deg[dst[i]], 1);
}

__global__ void scan1_kernel(const int* __restrict__ deg, int* __restrict__ local_excl,
                             int* __restrict__ blocksum, int n) {
    __shared__ int tmp[1024];
    int i = blockIdx.x * 1024 + threadIdx.x;
    int v = (i < n) ? deg[i] : 0;
    tmp[threadIdx.x] = v;
    __syncthreads();
    for (int off = 1; off < 1024; off <<= 1) {
        int t = 0;
        if (threadIdx.x >= off) t = tmp[threadIdx.x - off];
        __syncthreads();
        if (threadIdx.x >= off) tmp[threadIdx.x] += t;
        __syncthreads();
    }
    int incl = tmp[threadIdx.x];
    if (i < n) local_excl[i] = incl - v;
    if (threadIdx.x == 1023) blocksum[blockIdx.x] = tmp[1023];
}

__global__ void scan2_kernel(int* __restrict__ blocksum, int nb) {
    __shared__ int tmp[1024];
    int v = (threadIdx.x < nb) ? blocksum[threadIdx.x] : 0;
    tmp[threadIdx.x] = v;
    __syncthreads();
    for (int off = 1; off < 1024; off <<= 1) {
        int t = 0;
        if (threadIdx.x >= off) t = tmp[threadIdx.x - off];
        __syncthreads();
        if (threadIdx.x >= off) tmp[threadIdx.x] += t;
        __syncthreads();
    }
    if (threadIdx.x < nb) blocksum[threadIdx.x] = tmp[threadIdx.x] - v;  // exclusive
}

__global__ void scan3_kernel(const int* __restrict__ deg, const int* __restrict__ local_excl,
                             const int* __restrict__ blocksum, int* __restrict__ row_start,
                             int* __restrict__ cursor, float* __restrict__ inv_deg,
                             int n, int n_edges) {
    int i = blockIdx.x * 1024 + threadIdx.x;
    if (i < n) {
        int rs = local_excl[i] + blocksum[blockIdx.x];
        row_start[i] = rs;
        cursor[i]    = rs;
        inv_deg[i]   = 1.0f / fmaxf((float)deg[i], 1.0f);
    }
    if (i == 0) row_start[n] = n_edges;
}

// csr[] holds BYTE offsets of the fp8 source row (src * D = src * 128).
// fp16 consumers shift left by 1 (row = 256B).
__global__ void scatter_kernel(const int* __restrict__ src, const int* __restrict__ dst,
                               int* __restrict__ cursor, int* __restrict__ csr, int E) {
    int i = blockIdx.x * blockDim.x + threadIdx.x;
    if (i < E) {
        int d = dst[i];
        int p = atomicAdd(&cursor[d], 1);
        csr[p] = src[i] << 7;   // * 128 bytes per fp8 row
    }
}

// ---------------- weight transpose (W[l][f][k] -> Wt[l][k][f]) ----------------

__global__ void transpose_w(const float* __restrict__ Wl, const float* __restrict__ Wr,
                            float* __restrict__ Wlt, float* __restrict__ Wrt, int total) {
    int i = blockIdx.x * blockDim.x + threadIdx.x;
    if (i < total) {
        int l = i >> 14;
        int r = i & 16383;
        int f = r >> 7;
        int k = r & 127;
        int o = (l << 14) + (k << 7) + f;
        Wlt[o] = Wl[i];
        Wrt[o] = Wr[i];
    }
}

// ---------------- initial fp32 -> fp8(e4m3, x16) shadow copy ----------------

__global__ void x_to_fp8(const float* __restrict__ x, unsigned* __restrict__ xq, int total4) {
    int i = blockIdx.x * blockDim.x + threadIdx.x;   // one float4 -> one u32
    if (i < total4) {
        float4 v = ((const float4*)x)[i];
        unsigned u = 0;
        u = __builtin_amdgcn_cvt_pk_fp8_f32(v.x * Q8_SCALE, v.y * Q8_SCALE, u, false);
        u = __builtin_amdgcn_cvt_pk_fp8_f32(v.z * Q8_SCALE, v.w * Q8_SCALE, u, true);
        xq[i] = u;
    }
}

// ---------------- fused SAGE layer ----------------
// r15: TM 16->32. r14 post-mortem: per-layer time is pinned by VMEM
// INSTRUCTION count, 88% of which is Phase B weight loads (blocks x waves
// x 32k x 8 dwordx4) -- invariant across fp32/fp16/fp8 gathers, which is
// why shrinking gather bytes stopped paying. Doubling nodes/block halves
// weight instrs per node. Phase A fp8 uses 8-lane groups (128B row = 8 x
// dwordx4), so one instr covers 8 edges (2x r14) and 4 blocks x 32 groups
// keeps the same 128 concurrent node-chains per CU.
// Phase B: thread = 8 feats x 4 nodes, node map j = tn + 8q so each
// ds_read_b128 hits 8 consecutive LDS rows -> all 32 banks, conflict-free.
// INFMT/OUTFMT: 0=fp8, 1=fp16, 2=none(skip shadow write).
#define FMA4(ACC, W, S) ACC.x += W.x * (S); ACC.y += W.y * (S); \
                        ACC.z += W.z * (S); ACC.w += W.w * (S);

// fp16: accumulate 8 features (one dwordx4) into sA/sB.
#define ACC8(V) { const __half2* hp_ = (const __half2*)&(V);                 \
    float2 f0_ = __half22float2(hp_[0]); float2 f1_ = __half22float2(hp_[1]);\
    float2 f2_ = __half22float2(hp_[2]); float2 f3_ = __half22float2(hp_[3]);\
    sA.x += f0_.x; sA.y += f0_.y; sA.z += f1_.x; sA.w += f1_.y;              \
    sB.x += f2_.x; sB.y += f2_.y; sB.z += f3_.x; sB.w += f3_.y; }

// fp8: accumulate 16 features (one dwordx4) into s0..s3 via HW cvt.
#define ACC16Q(V) {                                                          \
    f2v a0_ = __builtin_amdgcn_cvt_pk_f32_fp8((int)(V).x, false);            \
    f2v a1_ = __builtin_amdgcn_cvt_pk_f32_fp8((int)(V).x, true);             \
    f2v b0_ = __builtin_amdgcn_cvt_pk_f32_fp8((int)(V).y, false);            \
    f2v b1_ = __builtin_amdgcn_cvt_pk_f32_fp8((int)(V).y, true);             \
    f2v c0_ = __builtin_amdgcn_cvt_pk_f32_fp8((int)(V).z, false);            \
    f2v c1_ = __builtin_amdgcn_cvt_pk_f32_fp8((int)(V).z, true);             \
    f2v d0_ = __builtin_amdgcn_cvt_pk_f32_fp8((int)(V).w, false);            \
    f2v d1_ = __builtin_amdgcn_cvt_pk_f32_fp8((int)(V).w, true);             \
    s0.x += a0_.x; s0.y += a0_.y; s0.z += a1_.x; s0.w += a1_.y;              \
    s1.x += b0_.x; s1.y += b0_.y; s1.z += b1_.x; s1.w += b1_.y;              \
    s2.x += c0_.x; s2.y += c0_.y; s2.z += c1_.x; s2.w += c1_.y;              \
    s3.x += d0_.x; s3.y += d0_.y; s3.z += d1_.x; s3.w += d1_.y; }

template<int INFMT, int OUTFMT>
__global__ __launch_bounds__(256, 4)
void sage_layer(const float* __restrict__ xin,
                const void* __restrict__ xq_in,
                float* __restrict__ xout,
                void* __restrict__ xq_out,
                const int* __restrict__ row_start, const int* __restrict__ csr,
                const float* __restrict__ inv_deg,
                const float* __restrict__ Wlt, const float* __restrict__ Wrt,
                const float* __restrict__ bl, int n_nodes) {
    __shared__ __align__(16) float A[TM][DP];
    __shared__ __align__(16) float X[TM][DP];
    int block0 = blockIdx.x * TM;
    int tid = threadIdx.x;

    // X-tile fill: TM*32 float4s, 4 per thread, nt loads (stream, read once).
    {
        for (int idx = tid; idx < TM * 32; idx += 256) {
            int row = idx >> 5, c4 = idx & 31;
            int nn = block0 + row;
            f4v v = {0.f, 0.f, 0.f, 0.f};
            if (nn < n_nodes)
                v = __builtin_nontemporal_load((const f4v*)(xin + (size_t)nn * D) + c4);
            *((f4v*)X[row] + c4) = v;
        }
    }

    // Phase A
    if constexpr (INFMT == 0) {
        // fp8: 8-lane group per node, 32 concurrent groups, 4-deep pipeline,
        // one dwordx4 = 16 features/lane; one instr = 8 edges.
        int g   = tid >> 3;       // 0..31
        int sub = tid & 7;
        int n = block0 + g;
        float4 s0 = {0,0,0,0}, s1 = {0,0,0,0}, s2 = {0,0,0,0}, s3 = {0,0,0,0};
        float idg = 1.f;
        int e0 = 0, e1 = 0;
        if (n < n_nodes) {
            e0 = row_start[n];
            e1 = row_start[n + 1];
            idg = inv_deg[n];
        }
        int e = e0;
        if (e < e1) {
            int last = e1 - 1;
            const char* qbase = (const char*)xq_in;
            int laneoff = sub * 16;   // 16B per lane within 128B fp8 row
            int i0 = csr[min(e,     last)];
            int i1 = csr[min(e + 1, last)];
            int i2 = csr[min(e + 2, last)];
            int i3 = csr[min(e + 3, last)];
            while (1) {
                uint4 v0 = *(const uint4*)(qbase + (size_t)(i0 + laneoff));
                uint4 v1 = *(const uint4*)(qbase + (size_t)(i1 + laneoff));
                uint4 v2 = *(const uint4*)(qbase + (size_t)(i2 + laneoff));
                uint4 v3 = *(const uint4*)(qbase + (size_t)(i3 + laneoff));
                int en = e + 4;
                bool more = en < e1;
                int p0, p1, p2, p3;
                if (more) {
                    p0 = csr[min(en,     last)];
                    p1 = csr[min(en + 1, last)];
                    p2 = csr[min(en + 2, last)];
                    p3 = csr[min(en + 3, last)];
                }
                ACC16Q(v0)
                if (e + 1 <= last) ACC16Q(v1)
                if (e + 2 <= last) ACC16Q(v2)
                if (e + 3 <= last) ACC16Q(v3)
                if (!more) break;
                e = en;
                i0 = p0; i1 = p1; i2 = p2; i3 = p3;
            }
        }
        float sc = idg * Q8_INV;
        s0.x *= sc; s0.y *= sc; s0.z *= sc; s0.w *= sc;
        s1.x *= sc; s1.y *= sc; s1.z *= sc; s1.w *= sc;
        s2.x *= sc; s2.y *= sc; s2.z *= sc; s2.w *= sc;
        s3.x *= sc; s3.y *= sc; s3.z *= sc; s3.w *= sc;
        ((float4*)A[g])[sub * 4 + 0] = s0;
        ((float4*)A[g])[sub * 4 + 1] = s1;
        ((float4*)A[g])[sub * 4 + 2] = s2;
        ((float4*)A[g])[sub * 4 + 3] = s3;
    } else {
        // fp16: 16-lane group, 2 sequential nodes per group.
        int g   = tid >> 4;       // 0..15
        int sub = tid & 15;
        const char* hbase = (const char*)xq_in;
        int laneoff = sub * 16;   // 16B per lane within 256B fp16 row
        for (int t = 0; t < 2; ++t) {
            int j = g + t * 16;
            int n = block0 + j;
            float4 sA = {0,0,0,0}, sB = {0,0,0,0};
            float idg = 1.f;
            int e0 = 0, e1 = 0;
            if (n < n_nodes) {
                e0 = row_start[n];
                e1 = row_start[n + 1];
                idg = inv_deg[n];
            }
            int e = e0;
            if (e < e1) {
                int last = e1 - 1;
                int i0 = csr[min(e,     last)] << 1;
                int i1 = csr[min(e + 1, last)] << 1;
                int i2 = csr[min(e + 2, last)] << 1;
                int i3 = csr[min(e + 3, last)] << 1;
                while (1) {
                    float4 v0 = *(const float4*)(hbase + (size_t)(i0 + laneoff));
                    float4 v1 = *(const float4*)(hbase + (size_t)(i1 + laneoff));
                    float4 v2 = *(const float4*)(hbase + (size_t)(i2 + laneoff));
                    float4 v3 = *(const float4*)(hbase + (size_t)(i3 + laneoff));
                    int en = e + 4;
                    bool more = en < e1;
                    int p0, p1, p2, p3;
                    if (more) {
                        p0 = csr[min(en,     last)] << 1;
                        p1 = csr[min(en + 1, last)] << 1;
                        p2 = csr[min(en + 2, last)] << 1;
                        p3 = csr[min(en + 3, last)] << 1;
                    }
                    ACC8(v0)
                    if (e + 1 <= last) ACC8(v1)
                    if (e + 2 <= last) ACC8(v2)
                    if (e + 3 <= last) ACC8(v3)
                    if (!more) break;
                    e = en;
                    i0 = p0; i1 = p1; i2 = p2; i3 = p3;
                }
            }
            sA.x *= idg; sA.y *= idg; sA.z *= idg; sA.w *= idg;
            sB.x *= idg; sB.y *= idg; sB.z *= idg; sB.w *= idg;
            ((float4*)A[j])[sub * 2]     = sA;
            ((float4*)A[j])[sub * 2 + 1] = sB;
        }
    }
    __syncthreads();

    // Phase B: wave w owns feature float4-columns [w*8, w*8+8) for all 32
    // nodes. Thread = 8 features x 4 nodes (j = tn + 8q), k-step 4.
    {
        int lane = tid & 63;
        int w    = tid >> 6;
        int c8   = lane & 7;        // float4 col within wave slice
        int tn   = lane >> 3;       // 0..7
        int cols4 = w * 8 + c8;     // global float4 col 0..31
        const float4* wlp = (const float4*)Wlt + cols4;   // row k at wlp[k*32]
        const float4* wrp = (const float4*)Wrt + cols4;
        float4 bv = ((const float4*)bl)[cols4];
        float4 acc0 = bv, acc1 = bv, acc2 = bv, acc3 = bv;
        const float* Ar0 = A[tn];
        const float* Ar1 = A[tn + 8];
        const float* Ar2 = A[tn + 16];
        const float* Ar3 = A[tn + 24];
        const float* Xr0 = X[tn];
        const float* Xr1 = X[tn + 8];
        const float* Xr2 = X[tn + 16];
        const float* Xr3 = X[tn + 24];

        for (int k = 0; k < D; k += 4) {
            float4 wl0 = wlp[(k + 0) * 32];
            float4 wl1 = wlp[(k + 1) * 32];
            float4 wl2 = wlp[(k + 2) * 32];
            float4 wl3 = wlp[(k + 3) * 32];
            float4 wr0 = wrp[(k + 0) * 32];
            float4 wr1 = wrp[(k + 1) * 32];
            float4 wr2 = wrp[(k + 2) * 32];
            float4 wr3 = wrp[(k + 3) * 32];
            float4 a0 = *(const float4*)&Ar0[k];
            float4 a1 = *(const float4*)&Ar1[k];
            float4 a2 = *(const float4*)&Ar2[k];
            float4 a3 = *(const float4*)&Ar3[k];
            float4 x0 = *(const float4*)&Xr0[k];
            float4 x1 = *(const float4*)&Xr1[k];
            float4 x2 = *(const float4*)&Xr2[k];
            float4 x3 = *(const float4*)&Xr3[k];

            FMA4(acc0, wl0, a0.x) FMA4(acc0, wl1, a0.y)
            FMA4(acc0, wl2, a0.z) FMA4(acc0, wl3, a0.w)
            FMA4(acc0, wr0, x0.x) FMA4(acc0, wr1, x0.y)
            FMA4(acc0, wr2, x0.z) FMA4(acc0, wr3, x0.w)
            FMA4(acc1, wl0, a1.x) FMA4(acc1, wl1, a1.y)
            FMA4(acc1, wl2, a1.z) FMA4(acc1, wl3, a1.w)
            FMA4(acc1, wr0, x1.x) FMA4(acc1, wr1, x1.y)
            FMA4(acc1, wr2, x1.z) FMA4(acc1, wr3, x1.w)
            FMA4(acc2, wl0, a2.x) FMA4(acc2, wl1, a2.y)
            FMA4(acc2, wl2, a2.z) FMA4(acc2, wl3, a2.w)
            FMA4(acc2, wr0, x2.x) FMA4(acc2, wr1, x2.y)
            FMA4(acc2, wr2, x2.z) FMA4(acc2, wr3, x2.w)
            FMA4(acc3, wl0, a3.x) FMA4(acc3, wl1, a3.y)
            FMA4(acc3, wl2, a3.z) FMA4(acc3, wl3, a3.w)
            FMA4(acc3, wr0, x3.x) FMA4(acc3, wr1, x3.y)
            FMA4(acc3, wr2, x3.z) FMA4(acc3, wr3, x3.w)
        }

        #pragma unroll
        for (int q = 0; q < 4; ++q) {
            int nn = block0 + tn + 8 * q;
            float4 acc = (q == 0) ? acc0 : (q == 1) ? acc1 : (q == 2) ? acc2 : acc3;
            if (nn < n_nodes) {
                f4v r;
                r.x = fmaxf(acc.x, 0.f); r.y = fmaxf(acc.y, 0.f);
                r.z = fmaxf(acc.z, 0.f); r.w = fmaxf(acc.w, 0.f);
                __builtin_nontemporal_store(r, (f4v*)xout + (size_t)nn * 32 + cols4);
                if constexpr (OUTFMT == 0) {
                    unsigned u = 0;
                    u = __builtin_amdgcn_cvt_pk_fp8_f32(r.x * Q8_SCALE, r.y * Q8_SCALE, u, false);
                    u = __builtin_amdgcn_cvt_pk_fp8_f32(r.z * Q8_SCALE, r.w * Q8_SCALE, u, true);
                    ((unsigned*)xq_out)[(size_t)nn * 32 + cols4] = u;
                } else if constexpr (OUTFMT == 1) {
                    __half2 h0 = __float22half2_rn(make_float2(r.x, r.y));
                    __half2 h1 = __float22half2_rn(make_float2(r.z, r.w));
                    uint2 u;
                    u.x = *(unsigned int*)&h0;
                    u.y = *(unsigned int*)&h1;
                    ((uint2*)xq_out)[(size_t)nn * 32 + cols4] = u;
                }
            }
        }
    }
}

extern "C" void kernel_launch(void* const* d_in, const int* in_sizes, int n_in,
                              void* d_out, int out_size, void* d_ws, size_t ws_size,
                              hipStream_t stream) {
    const float* x  = (const float*)d_in[0];
    const int*  edge = (const int*)d_in[1];
    const float* Wl = (const float*)d_in[2];
    const float* bl = (const float*)d_in[3];
    const float* Wr = (const float*)d_in[4];

    int N = in_sizes[0] / D;
    int E = in_sizes[1] / 2;
    int L = in_sizes[3] / D;   // 4
    const int* srcp = edge;
    const int* dstp = edge + E;

    char* w = (char*)d_ws;
    auto alloc = [&](size_t bytes) {
        char* p = w;
        w += (bytes + 255) & ~(size_t)255;
        return p;
    };
    int*   deg       = (int*)alloc((size_t)N * 4);
    int*   local_ex  = (int*)alloc((size_t)N * 4);
    int*   row_start = (int*)alloc((size_t)(N + 1) * 4);
    int*   cursor    = (int*)alloc((size_t)N * 4);
    int*   csr       = (int*)alloc((size_t)E * 4);
    float* invdeg    = (float*)alloc((size_t)N * 4);
    int*   blocksum  = (int*)alloc((size_t)1024 * 4);
    float* wlt       = (float*)alloc((size_t)L * D * D * 4);
    float* wrt       = (float*)alloc((size_t)L * D * D * 4);
    float* buf0      = (float*)alloc((size_t)N * D * 4);
    unsigned* q0     = (unsigned*)alloc((size_t)N * D);      // fp8 rows
    void*  q1        = (void*)alloc((size_t)N * D * 2);      // fp8 or fp16 rows

    int nb1 = (N + 1023) / 1024;
    hipMemsetAsync(deg, 0, (size_t)N * 4, stream);
    hist_kernel<<<(E + 255) / 256, 256, 0, stream>>>(dstp, deg, E);
    scan1_kernel<<<nb1, 1024, 0, stream>>>(deg, local_ex, blocksum, N);
    scan2_kernel<<<1, 1024, 0, stream>>>(blocksum, nb1);
    scan3_kernel<<<nb1, 1024, 0, stream>>>(deg, local_ex, blocksum, row_start,
                                           cursor, invdeg, N, E);
    scatter_kernel<<<(E + 255) / 256, 256, 0, stream>>>(srcp, dstp, cursor, csr, E);
    int tw = L * D * D;
    transpose_w<<<(tw + 255) / 256, 256, 0, stream>>>(Wl, Wr, wlt, wrt, tw);
    int t4 = N * (D / 4);
    x_to_fp8<<<(t4 + 255) / 256, 256, 0, stream>>>(x, q0, t4);

    float* out = (float*)d_out;
    int nbl = (N + TM - 1) / TM;
    size_t DD = (size_t)D * D;

    // l0: gather fp8(x) -> write fp8          fp32: x    -> buf0
    sage_layer<0, 0><<<nbl, 256, 0, stream>>>(x, q0, buf0, q1, row_start, csr, invdeg,
                                              wlt + 0 * DD, wrt + 0 * DD, bl + 0 * D, N);
    // l1: gather fp8 -> write fp8             fp32: buf0 -> out
    sage_layer<0, 0><<<nbl, 256, 0, stream>>>(buf0, q1, out, q0, row_start, csr, invdeg,
                                              wlt + 1 * DD, wrt + 1 * DD, bl + 1 * D, N);
    // l2: gather fp8 -> write FP16 (hedge)    fp32: out  -> buf0
    sage_layer<0, 1><<<nbl, 256, 0, stream>>>(out, q0, buf0, q1, row_start, csr, invdeg,
                                              wlt + 2 * DD, wrt + 2 * DD, bl + 2 * D, N);
    // l3: gather fp16 -> no shadow write      fp32: buf0 -> out (final)
    sage_layer<1, 2><<<nbl, 256, 0, stream>>>(buf0, q1, out, nullptr, row_start, csr, invdeg,
                                              wlt + 3 * DD, wrt + 3 * DD, bl + 3 * D, N);
}

// Round 7
// 619.683 us; speedup vs baseline: 1.9213x; 1.3356x over previous
//
#include <hip/hip_runtime.h>
#include <hip/hip_fp16.h>

#define D 128
#define DP 132   // classic-kernel fp32 LDS row stride
#define TM 32    // nodes per block
#define AHP 264  // MFMA A-tile halves/row: 528B, +16B pad -> <=2-way bank alias

typedef float f4v __attribute__((ext_vector_type(4)));
typedef float f2v __attribute__((ext_vector_type(2)));
typedef _Float16 h8v __attribute__((ext_vector_type(8)));

#define Q8_SCALE 16.0f      // fp8 storage scale: |act|*16 << 448 (e4m3 max)
#define Q8_INV   0.0625f

static __device__ __forceinline__ unsigned pkh(float a, float b) {
    __half2 h = __float22half2_rn(make_float2(a, b));
    return *(unsigned*)&h;
}

// ---------------- CSR build ----------------

__global__ void hist_kernel(const int* __restrict__ dst, int* __restrict__ deg, int E) {
    int i = blockIdx.x * blockDim.x + threadIdx.x;
    if (i < E) atomicAdd(&deg[dst[i]], 1);
}

__global__ void scan1_kernel(const int* __restrict__ deg, int* __restrict__ local_excl,
                             int* __restrict__ blocksum, int n) {
    __shared__ int tmp[1024];
    int i = blockIdx.x * 1024 + threadIdx.x;
    int v = (i < n) ? deg[i] : 0;
    tmp[threadIdx.x] = v;
    __syncthreads();
    for (int off = 1; off < 1024; off <<= 1) {
        int t = 0;
        if (threadIdx.x >= off) t = tmp[threadIdx.x - off];
        __syncthreads();
        if (threadIdx.x >= off) tmp[threadIdx.x] += t;
        __syncthreads();
    }
    int incl = tmp[threadIdx.x];
    if (i < n) local_excl[i] = incl - v;
    if (threadIdx.x == 1023) blocksum[blockIdx.x] = tmp[1023];
}

__global__ void scan2_kernel(int* __restrict__ blocksum, int nb) {
    __shared__ int tmp[1024];
    int v = (threadIdx.x < nb) ? blocksum[threadIdx.x] : 0;
    tmp[threadIdx.x] = v;
    __syncthreads();
    for (int off = 1; off < 1024; off <<= 1) {
        int t = 0;
        if (threadIdx.x >= off) t = tmp[threadIdx.x - off];
        __syncthreads();
        if (threadIdx.x >= off) tmp[threadIdx.x] += t;
        __syncthreads();
    }
    if (threadIdx.x < nb) blocksum[threadIdx.x] = tmp[threadIdx.x] - v;  // exclusive
}

__global__ void scan3_kernel(const int* __restrict__ deg, const int* __restrict__ local_excl,
                             const int* __restrict__ blocksum, int* __restrict__ row_start,
                             int* __restrict__ cursor, float* __restrict__ inv_deg,
                             int n, int n_edges) {
    int i = blockIdx.x * 1024 + threadIdx.x;
    if (i < n) {
        int rs = local_excl[i] + blocksum[blockIdx.x];
        row_start[i] = rs;
        cursor[i]    = rs;
        inv_deg[i]   = 1.0f / fmaxf((float)deg[i], 1.0f);
    }
    if (i == 0) row_start[n] = n_edges;
}

// csr[] holds BYTE offsets of the fp8 source row (src * 128).
__global__ void scatter_kernel(const int* __restrict__ src, const int* __restrict__ dst,
                               int* __restrict__ cursor, int* __restrict__ csr, int E) {
    int i = blockIdx.x * blockDim.x + threadIdx.x;
    if (i < E) {
        int d = dst[i];
        int p = atomicAdd(&cursor[d], 1);
        csr[p] = src[i] << 7;
    }
}

// ---------------- weight transpose (classic l3: W[l][f][k] -> Wt[l][k][f]) -------

__global__ void transpose_w(const float* __restrict__ Wl, const float* __restrict__ Wr,
                            float* __restrict__ Wlt, float* __restrict__ Wrt, int total) {
    int i = blockIdx.x * blockDim.x + threadIdx.x;
    if (i < total) {
        int l = i >> 14;
        int r = i & 16383;
        int f = r >> 7;
        int k = r & 127;
        int o = (l << 14) + (k << 7) + f;
        Wlt[o] = Wl[i];
        Wrt[o] = Wr[i];
    }
}

// ---------------- MFMA weight prepack ----------------
// Fragment-order fp16 pack for mfma_f32_16x16x32_f16, swapped-operand use:
// A-operand = weight tile, lane l holds row f = ft*16+(l&15),
// k = ks*32 + (l>>4)*8 + j (j=0..7). K-concat: ks 0..3 -> Wl (agg path),
// ks 4..7 -> Wr (x path). One thread emits one lane's 8 halves (16B), so a
// fragment = 64 consecutive uint4 = 1KB contiguous -> frag loads in the
// layer kernel are unique-data coalesced dwordx4.
__global__ void prepack_w(const float* __restrict__ Wl, const float* __restrict__ Wr,
                          __half* __restrict__ wpack, int total) {
    int t = blockIdx.x * blockDim.x + threadIdx.x;   // ((l*8+ft)*8+ks)*64+lane
    if (t >= total) return;
    int lane = t & 63;
    int ks   = (t >> 6) & 7;
    int ft   = (t >> 9) & 7;
    int l    = t >> 12;
    int f = ft * 16 + (lane & 15);
    int k = (ks & 3) * 32 + ((lane >> 4) << 3);
    const float* W = (ks < 4) ? Wl : Wr;
    const float* src = W + ((size_t)l << 14) + ((size_t)f << 7) + k;
    float4 v0 = *(const float4*)src;
    float4 v1 = *(const float4*)(src + 4);
    uint4 u = {pkh(v0.x, v0.y), pkh(v0.z, v0.w), pkh(v1.x, v1.y), pkh(v1.z, v1.w)};
    ((uint4*)wpack)[t] = u;
}

// ---------------- initial fp32 -> fp8(e4m3, x16) shadow copy ----------------

__global__ void x_to_fp8(const float* __restrict__ x, unsigned* __restrict__ xq, int total4) {
    int i = blockIdx.x * blockDim.x + threadIdx.x;
    if (i < total4) {
        float4 v = ((const float4*)x)[i];
        unsigned u = 0;
        u = __builtin_amdgcn_cvt_pk_fp8_f32(v.x * Q8_SCALE, v.y * Q8_SCALE, u, false);
        u = __builtin_amdgcn_cvt_pk_fp8_f32(v.z * Q8_SCALE, v.w * Q8_SCALE, u, true);
        xq[i] = u;
    }
}

// ---------------- fp8 gather helpers ----------------

#define ACC16Q(V) {                                                          \
    f2v a0_ = __builtin_amdgcn_cvt_pk_f32_fp8((int)(V).x, false);            \
    f2v a1_ = __builtin_amdgcn_cvt_pk_f32_fp8((int)(V).x, true);             \
    f2v b0_ = __builtin_amdgcn_cvt_pk_f32_fp8((int)(V).y, false);            \
    f2v b1_ = __builtin_amdgcn_cvt_pk_f32_fp8((int)(V).y, true);             \
    f2v c0_ = __builtin_amdgcn_cvt_pk_f32_fp8((int)(V).z, false);            \
    f2v c1_ = __builtin_amdgcn_cvt_pk_f32_fp8((int)(V).z, true);             \
    f2v d0_ = __builtin_amdgcn_cvt_pk_f32_fp8((int)(V).w, false);            \
    f2v d1_ = __builtin_amdgcn_cvt_pk_f32_fp8((int)(V).w, true);             \
    s0.x += a0_.x; s0.y += a0_.y; s0.z += a1_.x; s0.w += a1_.y;              \
    s1.x += b0_.x; s1.y += b0_.y; s1.z += b1_.x; s1.w += b1_.y;              \
    s2.x += c0_.x; s2.y += c0_.y; s2.z += c1_.x; s2.w += c1_.y;              \
    s3.x += d0_.x; s3.y += d0_.y; s3.z += d1_.x; s3.w += d1_.y; }

#define FMA4(ACC, W, S) ACC.x += W.x * (S); ACC.y += W.y * (S); \
                        ACC.z += W.z * (S); ACC.w += W.w * (S);

#define ACC8(V) { const __half2* hp_ = (const __half2*)&(V);                 \
    float2 f0_ = __half22float2(hp_[0]); float2 f1_ = __half22float2(hp_[1]);\
    float2 f2_ = __half22float2(hp_[2]); float2 f3_ = __half22float2(hp_[3]);\
    sA.x += f0_.x; sA.y += f0_.y; sA.z += f1_.x; sA.w += f1_.y;              \
    sB.x += f2_.x; sB.y += f2_.y; sB.z += f3_.x; sB.w += f3_.y; }

// ---------------- MFMA fused SAGE layer (layers 0..2) ----------------
// r16: Phase B moved to matrix cores. r15 post-mortem: 75% of the 160us
// layer was Phase B (fmac VALU ~100K cy + weight dwordx4 L1-return ~200K cy)
// with MfmaUtil=0. Per block D = Wcat x [agg|x]: M=128 feats, N=32 nodes,
// K=256, mfma_f32_16x16x32_f16, swapped operands so each lane ends with 4
// CONSECUTIVE features of one node (direct float4 + packed-fp8 stores).
// Weights: fragment-prepacked fp16 (prepack_w) -> 16 coalesced dwordx4
// preloads per wave, issued before the barrier so L2 latency hides under
// the gather. A-tile [agg|x] fp16 in LDS, row pad 16B.
// OUTFMT: 0 = fp8 shadow out, 1 = fp16 shadow out.
template<int OUTFMT>
__global__ __launch_bounds__(256, 4)
void sage_layer_mfma(const float* __restrict__ xin,
                     const void* __restrict__ xq_in,
                     float* __restrict__ xout,
                     void* __restrict__ xq_out,
                     const int* __restrict__ row_start, const int* __restrict__ csr,
                     const float* __restrict__ inv_deg,
                     const __half* __restrict__ wpack,
                     const float* __restrict__ bl, int n_nodes) {
    __shared__ __align__(16) __half Ah[TM][AHP];
    int block0 = blockIdx.x * TM;
    int tid = threadIdx.x;
    int lane = tid & 63;
    int wv   = tid >> 6;

    // X-fill: x (fp32, nt) -> fp16 into columns 128..255 of A-tile.
    {
        int row = tid >> 3;          // 0..31
        int seg = tid & 7;           // 16 halves per thread
        int nn = block0 + row;
        f4v v0 = {0,0,0,0}, v1 = v0, v2 = v0, v3 = v0;
        if (nn < n_nodes) {
            const f4v* xp = (const f4v*)(xin + (size_t)nn * D) + seg * 4;
            v0 = __builtin_nontemporal_load(xp);
            v1 = __builtin_nontemporal_load(xp + 1);
            v2 = __builtin_nontemporal_load(xp + 2);
            v3 = __builtin_nontemporal_load(xp + 3);
        }
        uint4 ua = {pkh(v0.x,v0.y), pkh(v0.z,v0.w), pkh(v1.x,v1.y), pkh(v1.z,v1.w)};
        uint4 ub = {pkh(v2.x,v2.y), pkh(v2.z,v2.w), pkh(v3.x,v3.y), pkh(v3.z,v3.w)};
        uint4* dst = (uint4*)&Ah[row][128 + seg * 16];
        dst[0] = ua; dst[1] = ub;
    }

    // Phase A: fp8 gather, 8-lane group per node (r15 structure), fp32 acc,
    // fp16 write to columns 0..127.
    {
        int g   = tid >> 3;       // 0..31
        int sub = tid & 7;
        int n = block0 + g;
        float4 s0 = {0,0,0,0}, s1 = {0,0,0,0}, s2 = {0,0,0,0}, s3 = {0,0,0,0};
        float idg = 1.f;
        int e0 = 0, e1 = 0;
        if (n < n_nodes) {
            e0 = row_start[n];
            e1 = row_start[n + 1];
            idg = inv_deg[n];
        }
        int e = e0;
        if (e < e1) {
            int last = e1 - 1;
            const char* qbase = (const char*)xq_in;
            int laneoff = sub * 16;
            int i0 = csr[min(e,     last)];
            int i1 = csr[min(e + 1, last)];
            int i2 = csr[min(e + 2, last)];
            int i3 = csr[min(e + 3, last)];
            while (1) {
                uint4 v0 = *(const uint4*)(qbase + (size_t)(i0 + laneoff));
                uint4 v1 = *(const uint4*)(qbase + (size_t)(i1 + laneoff));
                uint4 v2 = *(const uint4*)(qbase + (size_t)(i2 + laneoff));
                uint4 v3 = *(const uint4*)(qbase + (size_t)(i3 + laneoff));
                int en = e + 4;
                bool more = en < e1;
                int p0, p1, p2, p3;
                if (more) {
                    p0 = csr[min(en,     last)];
                    p1 = csr[min(en + 1, last)];
                    p2 = csr[min(en + 2, last)];
                    p3 = csr[min(en + 3, last)];
                }
                ACC16Q(v0)
                if (e + 1 <= last) ACC16Q(v1)
                if (e + 2 <= last) ACC16Q(v2)
                if (e + 3 <= last) ACC16Q(v3)
                if (!more) break;
                e = en;
                i0 = p0; i1 = p1; i2 = p2; i3 = p3;
            }
        }
        float sc = idg * Q8_INV;
        uint4 ua = {pkh(s0.x*sc,s0.y*sc), pkh(s0.z*sc,s0.w*sc),
                    pkh(s1.x*sc,s1.y*sc), pkh(s1.z*sc,s1.w*sc)};
        uint4 ub = {pkh(s2.x*sc,s2.y*sc), pkh(s2.z*sc,s2.w*sc),
                    pkh(s3.x*sc,s3.y*sc), pkh(s3.z*sc,s3.w*sc)};
        uint4* dst = (uint4*)&Ah[g][sub * 16];
        dst[0] = ua; dst[1] = ub;
    }

    // Preload this wave's 16 weight fragments (2 f-tiles x 8 k-steps),
    // each a unique-data coalesced 1KB dwordx4. L2-hot after block 0.
    uint4 wf[16];
    {
        const uint4* wp = (const uint4*)wpack;
        #pragma unroll
        for (int i = 0; i < 16; ++i) {
            int ft = wv * 2 + (i >> 3);
            int ks = i & 7;
            wf[i] = wp[(size_t)(ft * 8 + ks) * 64 + lane];
        }
    }

    __syncthreads();

    // Phase B: wave wv owns feature tiles {2wv, 2wv+1} x node tiles {0,1}.
    {
        f4v acc[2][2];
        #pragma unroll
        for (int ft = 0; ft < 2; ++ft) {
            int f0 = wv * 32 + ft * 16 + ((lane >> 4) << 2);
            f4v bv = *(const f4v*)(bl + f0);
            acc[ft][0] = bv;
            acc[ft][1] = bv;
        }
        #pragma unroll
        for (int ks = 0; ks < 8; ++ks) {
            int koff = ks * 32 + ((lane >> 4) << 3);
            h8v b0 = *(const h8v*)&Ah[lane & 15][koff];
            h8v b1 = *(const h8v*)&Ah[16 + (lane & 15)][koff];
            h8v a0 = *(const h8v*)&wf[ks];
            h8v a1 = *(const h8v*)&wf[8 + ks];
            acc[0][0] = __builtin_amdgcn_mfma_f32_16x16x32_f16(a0, b0, acc[0][0], 0, 0, 0);
            acc[0][1] = __builtin_amdgcn_mfma_f32_16x16x32_f16(a0, b1, acc[0][1], 0, 0, 0);
            acc[1][0] = __builtin_amdgcn_mfma_f32_16x16x32_f16(a1, b0, acc[1][0], 0, 0, 0);
            acc[1][1] = __builtin_amdgcn_mfma_f32_16x16x32_f16(a1, b1, acc[1][1], 0, 0, 0);
        }
        // Epilogue: lane holds 4 consecutive feats of node (lane&15) per tile.
        #pragma unroll
        for (int ft = 0; ft < 2; ++ft) {
            #pragma unroll
            for (int nt = 0; nt < 2; ++nt) {
                int node = block0 + nt * 16 + (lane & 15);
                int f0 = wv * 32 + ft * 16 + ((lane >> 4) << 2);
                f4v r = acc[ft][nt];
                r.x = fmaxf(r.x, 0.f); r.y = fmaxf(r.y, 0.f);
                r.z = fmaxf(r.z, 0.f); r.w = fmaxf(r.w, 0.f);
                if (node < n_nodes) {
                    __builtin_nontemporal_store(r, (f4v*)(xout + (size_t)node * D + f0));
                    if constexpr (OUTFMT == 0) {
                        unsigned u = 0;
                        u = __builtin_amdgcn_cvt_pk_fp8_f32(r.x * Q8_SCALE, r.y * Q8_SCALE, u, false);
                        u = __builtin_amdgcn_cvt_pk_fp8_f32(r.z * Q8_SCALE, r.w * Q8_SCALE, u, true);
                        ((unsigned*)xq_out)[(size_t)node * 32 + (f0 >> 2)] = u;
                    } else {
                        uint2 u = {pkh(r.x, r.y), pkh(r.z, r.w)};
                        ((uint2*)xq_out)[(size_t)node * 32 + (f0 >> 2)] = u;
                    }
                }
            }
        }
    }
}

// ---------------- classic fp32-GEMM layer (layer 3, precision hedge) -------
// r15 structure: fp16 gather (16-lane groups, 2 nodes each), fp32 GEMM from
// LDS, no shadow write.
__global__ __launch_bounds__(256, 4)
void sage_layer_fp16(const float* __restrict__ xin,
                     const void* __restrict__ xq_in,
                     float* __restrict__ xout,
                     const int* __restrict__ row_start, const int* __restrict__ csr,
                     const float* __restrict__ inv_deg,
                     const float* __restrict__ Wlt, const float* __restrict__ Wrt,
                     const float* __restrict__ bl, int n_nodes) {
    __shared__ __align__(16) float A[TM][DP];
    __shared__ __align__(16) float X[TM][DP];
    int block0 = blockIdx.x * TM;
    int tid = threadIdx.x;

    {
        for (int idx = tid; idx < TM * 32; idx += 256) {
            int row = idx >> 5, c4 = idx & 31;
            int nn = block0 + row;
            f4v v = {0.f, 0.f, 0.f, 0.f};
            if (nn < n_nodes)
                v = __builtin_nontemporal_load((const f4v*)(xin + (size_t)nn * D) + c4);
            *((f4v*)X[row] + c4) = v;
        }
    }

    {
        int g   = tid >> 4;
        int sub = tid & 15;
        const char* hbase = (const char*)xq_in;
        int laneoff = sub * 16;
        for (int t = 0; t < 2; ++t) {
            int j = g + t * 16;
            int n = block0 + j;
            float4 sA = {0,0,0,0}, sB = {0,0,0,0};
            float idg = 1.f;
            int e0 = 0, e1 = 0;
            if (n < n_nodes) {
                e0 = row_start[n];
                e1 = row_start[n + 1];
                idg = inv_deg[n];
            }
            int e = e0;
            if (e < e1) {
                int last = e1 - 1;
                int i0 = csr[min(e,     last)] << 1;
                int i1 = csr[min(e + 1, last)] << 1;
                int i2 = csr[min(e + 2, last)] << 1;
                int i3 = csr[min(e + 3, last)] << 1;
                while (1) {
                    float4 v0 = *(const float4*)(hbase + (size_t)(i0 + laneoff));
                    float4 v1 = *(const float4*)(hbase + (size_t)(i1 + laneoff));
                    float4 v2 = *(const float4*)(hbase + (size_t)(i2 + laneoff));
                    float4 v3 = *(const float4*)(hbase + (size_t)(i3 + laneoff));
                    int en = e + 4;
                    bool more = en < e1;
                    int p0, p1, p2, p3;
                    if (more) {
                        p0 = csr[min(en,     last)] << 1;
                        p1 = csr[min(en + 1, last)] << 1;
                        p2 = csr[min(en + 2, last)] << 1;
                        p3 = csr[min(en + 3, last)] << 1;
                    }
                    ACC8(v0)
                    if (e + 1 <= last) ACC8(v1)
                    if (e + 2 <= last) ACC8(v2)
                    if (e + 3 <= last) ACC8(v3)
                    if (!more) break;
                    e = en;
                    i0 = p0; i1 = p1; i2 = p2; i3 = p3;
                }
            }
            sA.x *= idg; sA.y *= idg; sA.z *= idg; sA.w *= idg;
            sB.x *= idg; sB.y *= idg; sB.z *= idg; sB.w *= idg;
            ((float4*)A[j])[sub * 2]     = sA;
            ((float4*)A[j])[sub * 2 + 1] = sB;
        }
    }
    __syncthreads();

    {
        int lane = tid & 63;
        int w    = tid >> 6;
        int c8   = lane & 7;
        int tn   = lane >> 3;
        int cols4 = w * 8 + c8;
        const float4* wlp = (const float4*)Wlt + cols4;
        const float4* wrp = (const float4*)Wrt + cols4;
        float4 bv = ((const float4*)bl)[cols4];
        float4 acc0 = bv, acc1 = bv, acc2 = bv, acc3 = bv;
        const float* Ar0 = A[tn];
        const float* Ar1 = A[tn + 8];
        const float* Ar2 = A[tn + 16];
        const float* Ar3 = A[tn + 24];
        const float* Xr0 = X[tn];
        const float* Xr1 = X[tn + 8];
        const float* Xr2 = X[tn + 16];
        const float* Xr3 = X[tn + 24];

        for (int k = 0; k < D; k += 4) {
            float4 wl0 = wlp[(k + 0) * 32];
            float4 wl1 = wlp[(k + 1) * 32];
            float4 wl2 = wlp[(k + 2) * 32];
            float4 wl3 = wlp[(k + 3) * 32];
            float4 wr0 = wrp[(k + 0) * 32];
            float4 wr1 = wrp[(k + 1) * 32];
            float4 wr2 = wrp[(k + 2) * 32];
            float4 wr3 = wrp[(k + 3) * 32];
            float4 a0 = *(const float4*)&Ar0[k];
            float4 a1 = *(const float4*)&Ar1[k];
            float4 a2 = *(const float4*)&Ar2[k];
            float4 a3 = *(const float4*)&Ar3[k];
            float4 x0 = *(const float4*)&Xr0[k];
            float4 x1 = *(const float4*)&Xr1[k];
            float4 x2 = *(const float4*)&Xr2[k];
            float4 x3 = *(const float4*)&Xr3[k];

            FMA4(acc0, wl0, a0.x) FMA4(acc0, wl1, a0.y)
            FMA4(acc0, wl2, a0.z) FMA4(acc0, wl3, a0.w)
            FMA4(acc0, wr0, x0.x) FMA4(acc0, wr1, x0.y)
            FMA4(acc0, wr2, x0.z) FMA4(acc0, wr3, x0.w)
            FMA4(acc1, wl0, a1.x) FMA4(acc1, wl1, a1.y)
            FMA4(acc1, wl2, a1.z) FMA4(acc1, wl3, a1.w)
            FMA4(acc1, wr0, x1.x) FMA4(acc1, wr1, x1.y)
            FMA4(acc1, wr2, x1.z) FMA4(acc1, wr3, x1.w)
            FMA4(acc2, wl0, a2.x) FMA4(acc2, wl1, a2.y)
            FMA4(acc2, wl2, a2.z) FMA4(acc2, wl3, a2.w)
            FMA4(acc2, wr0, x2.x) FMA4(acc2, wr1, x2.y)
            FMA4(acc2, wr2, x2.z) FMA4(acc2, wr3, x2.w)
            FMA4(acc3, wl0, a3.x) FMA4(acc3, wl1, a3.y)
            FMA4(acc3, wl2, a3.z) FMA4(acc3, wl3, a3.w)
            FMA4(acc3, wr0, x3.x) FMA4(acc3, wr1, x3.y)
            FMA4(acc3, wr2, x3.z) FMA4(acc3, wr3, x3.w)
        }

        #pragma unroll
        for (int q = 0; q < 4; ++q) {
            int nn = block0 + tn + 8 * q;
            float4 acc = (q == 0) ? acc0 : (q == 1) ? acc1 : (q == 2) ? acc2 : acc3;
            if (nn < n_nodes) {
                f4v r;
                r.x = fmaxf(acc.x, 0.f); r.y = fmaxf(acc.y, 0.f);
                r.z = fmaxf(acc.z, 0.f); r.w = fmaxf(acc.w, 0.f);
                __builtin_nontemporal_store(r, (f4v*)xout + (size_t)nn * 32 + cols4);
            }
        }
    }
}

extern "C" void kernel_launch(void* const* d_in, const int* in_sizes, int n_in,
                              void* d_out, int out_size, void* d_ws, size_t ws_size,
                              hipStream_t stream) {
    const float* x  = (const float*)d_in[0];
    const int*  edge = (const int*)d_in[1];
    const float* Wl = (const float*)d_in[2];
    const float* bl = (const float*)d_in[3];
    const float* Wr = (const float*)d_in[4];

    int N = in_sizes[0] / D;
    int E = in_sizes[1] / 2;
    int L = in_sizes[3] / D;   // 4
    const int* srcp = edge;
    const int* dstp = edge + E;

    char* w = (char*)d_ws;
    auto alloc = [&](size_t bytes) {
        char* p = w;
        w += (bytes + 255) & ~(size_t)255;
        return p;
    };
    int*   deg       = (int*)alloc((size_t)N * 4);
    int*   local_ex  = (int*)alloc((size_t)N * 4);
    int*   row_start = (int*)alloc((size_t)(N + 1) * 4);
    int*   cursor    = (int*)alloc((size_t)N * 4);
    int*   csr       = (int*)alloc((size_t)E * 4);
    float* invdeg    = (float*)alloc((size_t)N * 4);
    int*   blocksum  = (int*)alloc((size_t)1024 * 4);
    float* wlt       = (float*)alloc((size_t)L * D * D * 4);
    float* wrt       = (float*)alloc((size_t)L * D * D * 4);
    __half* wpack    = (__half*)alloc((size_t)L * 32768 * 2);   // 64KB/layer
    float* buf0      = (float*)alloc((size_t)N * D * 4);
    unsigned* q0     = (unsigned*)alloc((size_t)N * D);         // fp8 rows
    void*  q1        = (void*)alloc((size_t)N * D * 2);         // fp8/fp16 rows

    int nb1 = (N + 1023) / 1024;
    hipMemsetAsync(deg, 0, (size_t)N * 4, stream);
    hist_kernel<<<(E + 255) / 256, 256, 0, stream>>>(dstp, deg, E);
    scan1_kernel<<<nb1, 1024, 0, stream>>>(deg, local_ex, blocksum, N);
    scan2_kernel<<<1, 1024, 0, stream>>>(blocksum, nb1);
    scan3_kernel<<<nb1, 1024, 0, stream>>>(deg, local_ex, blocksum, row_start,
                                           cursor, invdeg, N, E);
    scatter_kernel<<<(E + 255) / 256, 256, 0, stream>>>(srcp, dstp, cursor, csr, E);
    int tw = L * D * D;
    transpose_w<<<(tw + 255) / 256, 256, 0, stream>>>(Wl, Wr, wlt, wrt, tw);
    int tp = L * 4096;
    prepack_w<<<(tp + 255) / 256, 256, 0, stream>>>(Wl, Wr, wpack, tp);
    int t4 = N * (D / 4);
    x_to_fp8<<<(t4 + 255) / 256, 256, 0, stream>>>(x, q0, t4);

    float* out = (float*)d_out;
    int nbl = (N + TM - 1) / TM;
    size_t DD = (size_t)D * D;

    // l0: gather fp8(x) -> fp8 shadow         fp32: x    -> buf0
    sage_layer_mfma<0><<<nbl, 256, 0, stream>>>(x, q0, buf0, q1, row_start, csr, invdeg,
                                                wpack + 0 * 32768, bl + 0 * D, N);
    // l1: gather fp8 -> fp8 shadow            fp32: buf0 -> out
    sage_layer_mfma<0><<<nbl, 256, 0, stream>>>(buf0, q1, out, q0, row_start, csr, invdeg,
                                                wpack + 1 * 32768, bl + 1 * D, N);
    // l2: gather fp8 -> FP16 shadow (hedge)   fp32: out  -> buf0
    sage_layer_mfma<1><<<nbl, 256, 0, stream>>>(out, q0, buf0, q1, row_start, csr, invdeg,
                                                wpack + 2 * 32768, bl + 2 * D, N);
    // l3: classic fp32 GEMM, fp16 gather      fp32: buf0 -> out (final)
    sage_layer_fp16<<<nbl, 256, 0, stream>>>(buf0, q1, out, row_start, csr, invdeg,
                                             wlt + 3 * DD, wrt + 3 * DD,
                                             bl + 3 * D, N);
}

// Round 8
// 563.171 us; speedup vs baseline: 2.1141x; 1.1003x over previous
//
#include <hip/hip_runtime.h>
#include <hip/hip_fp16.h>

#define D 128
#define TM 32    // nodes per block
#define AHP 264  // MFMA A-tile halves/row: 528B, +16B pad -> <=2-way bank alias

typedef float f4v __attribute__((ext_vector_type(4)));
typedef float f2v __attribute__((ext_vector_type(2)));
typedef _Float16 h8v __attribute__((ext_vector_type(8)));

#define Q8_SCALE 16.0f      // fp8 storage scale: |act|*16 << 448 (e4m3 max)
#define Q8_INV   0.0625f

static __device__ __forceinline__ unsigned pkh(float a, float b) {
    __half2 h = __float22half2_rn(make_float2(a, b));
    return *(unsigned*)&h;
}

// ---------------- CSR build ----------------

__global__ void hist_kernel(const int* __restrict__ dst, int* __restrict__ deg, int E) {
    int i = blockIdx.x * blockDim.x + threadIdx.x;
    if (i < E) atomicAdd(&deg[dst[i]], 1);
}

__global__ void scan1_kernel(const int* __restrict__ deg, int* __restrict__ local_excl,
                             int* __restrict__ blocksum, int n) {
    __shared__ int tmp[1024];
    int i = blockIdx.x * 1024 + threadIdx.x;
    int v = (i < n) ? deg[i] : 0;
    tmp[threadIdx.x] = v;
    __syncthreads();
    for (int off = 1; off < 1024; off <<= 1) {
        int t = 0;
        if (threadIdx.x >= off) t = tmp[threadIdx.x - off];
        __syncthreads();
        if (threadIdx.x >= off) tmp[threadIdx.x] += t;
        __syncthreads();
    }
    int incl = tmp[threadIdx.x];
    if (i < n) local_excl[i] = incl - v;
    if (threadIdx.x == 1023) blocksum[blockIdx.x] = tmp[1023];
}

__global__ void scan2_kernel(int* __restrict__ blocksum, int nb) {
    __shared__ int tmp[1024];
    int v = (threadIdx.x < nb) ? blocksum[threadIdx.x] : 0;
    tmp[threadIdx.x] = v;
    __syncthreads();
    for (int off = 1; off < 1024; off <<= 1) {
        int t = 0;
        if (threadIdx.x >= off) t = tmp[threadIdx.x - off];
        __syncthreads();
        if (threadIdx.x >= off) tmp[threadIdx.x] += t;
        __syncthreads();
    }
    if (threadIdx.x < nb) blocksum[threadIdx.x] = tmp[threadIdx.x] - v;  // exclusive
}

__global__ void scan3_kernel(const int* __restrict__ deg, const int* __restrict__ local_excl,
                             const int* __restrict__ blocksum, int* __restrict__ row_start,
                             int* __restrict__ cursor, float* __restrict__ inv_deg,
                             int n, int n_edges) {
    int i = blockIdx.x * 1024 + threadIdx.x;
    if (i < n) {
        int rs = local_excl[i] + blocksum[blockIdx.x];
        row_start[i] = rs;
        cursor[i]    = rs;
        inv_deg[i]   = 1.0f / fmaxf((float)deg[i], 1.0f);
    }
    if (i == 0) row_start[n] = n_edges;
}

// csr[] holds BYTE offsets of the fp8 source row (src * 128).
__global__ void scatter_kernel(const int* __restrict__ src, const int* __restrict__ dst,
                               int* __restrict__ cursor, int* __restrict__ csr, int E) {
    int i = blockIdx.x * blockDim.x + threadIdx.x;
    if (i < E) {
        int d = dst[i];
        int p = atomicAdd(&cursor[d], 1);
        csr[p] = src[i] << 7;
    }
}

// ---------------- MFMA weight prepack ----------------
// Fragment-order fp16 pack for mfma_f32_16x16x32_f16, swapped-operand use:
// A-operand = weight tile, lane l holds row f = ft*16+(l&15),
// k = ks*32 + (l>>4)*8 + j (j=0..7). K-concat: ks 0..3 -> Wl (agg path),
// ks 4..7 -> Wr (x path). One thread emits one lane's 8 halves (16B), so a
// fragment = 64 consecutive uint4 = 1KB contiguous -> frag loads in the
// layer kernel are unique-data coalesced dwordx4.
__global__ void prepack_w(const float* __restrict__ Wl, const float* __restrict__ Wr,
                          __half* __restrict__ wpack, int total) {
    int t = blockIdx.x * blockDim.x + threadIdx.x;   // ((l*8+ft)*8+ks)*64+lane
    if (t >= total) return;
    int lane = t & 63;
    int ks   = (t >> 6) & 7;
    int ft   = (t >> 9) & 7;
    int l    = t >> 12;
    int f = ft * 16 + (lane & 15);
    int k = (ks & 3) * 32 + ((lane >> 4) << 3);
    const float* W = (ks < 4) ? Wl : Wr;
    const float* src = W + ((size_t)l << 14) + ((size_t)f << 7) + k;
    float4 v0 = *(const float4*)src;
    float4 v1 = *(const float4*)(src + 4);
    uint4 u = {pkh(v0.x, v0.y), pkh(v0.z, v0.w), pkh(v1.x, v1.y), pkh(v1.z, v1.w)};
    ((uint4*)wpack)[t] = u;
}

// ---------------- initial fp32 -> fp8(e4m3, x16) shadow copy ----------------

__global__ void x_to_fp8(const float* __restrict__ x, unsigned* __restrict__ xq, int total4) {
    int i = blockIdx.x * blockDim.x + threadIdx.x;
    if (i < total4) {
        float4 v = ((const float4*)x)[i];
        unsigned u = 0;
        u = __builtin_amdgcn_cvt_pk_fp8_f32(v.x * Q8_SCALE, v.y * Q8_SCALE, u, false);
        u = __builtin_amdgcn_cvt_pk_fp8_f32(v.z * Q8_SCALE, v.w * Q8_SCALE, u, true);
        xq[i] = u;
    }
}

// ---------------- gather helpers ----------------

#define ACC16Q(V) {                                                          \
    f2v a0_ = __builtin_amdgcn_cvt_pk_f32_fp8((int)(V).x, false);            \
    f2v a1_ = __builtin_amdgcn_cvt_pk_f32_fp8((int)(V).x, true);             \
    f2v b0_ = __builtin_amdgcn_cvt_pk_f32_fp8((int)(V).y, false);            \
    f2v b1_ = __builtin_amdgcn_cvt_pk_f32_fp8((int)(V).y, true);             \
    f2v c0_ = __builtin_amdgcn_cvt_pk_f32_fp8((int)(V).z, false);            \
    f2v c1_ = __builtin_amdgcn_cvt_pk_f32_fp8((int)(V).z, true);             \
    f2v d0_ = __builtin_amdgcn_cvt_pk_f32_fp8((int)(V).w, false);            \
    f2v d1_ = __builtin_amdgcn_cvt_pk_f32_fp8((int)(V).w, true);             \
    s0.x += a0_.x; s0.y += a0_.y; s0.z += a1_.x; s0.w += a1_.y;              \
    s1.x += b0_.x; s1.y += b0_.y; s1.z += b1_.x; s1.w += b1_.y;              \
    s2.x += c0_.x; s2.y += c0_.y; s2.z += c1_.x; s2.w += c1_.y;              \
    s3.x += d0_.x; s3.y += d0_.y; s3.z += d1_.x; s3.w += d1_.y; }

#define ACC8(V) { const __half2* hp_ = (const __half2*)&(V);                 \
    float2 f0_ = __half22float2(hp_[0]); float2 f1_ = __half22float2(hp_[1]);\
    float2 f2_ = __half22float2(hp_[2]); float2 f3_ = __half22float2(hp_[3]);\
    sA.x += f0_.x; sA.y += f0_.y; sA.z += f1_.x; sA.w += f1_.y;              \
    sB.x += f2_.x; sB.y += f2_.y; sB.z += f3_.x; sB.w += f3_.y; }

// ---------------- MFMA fused SAGE layer (all layers, r17) ----------------
// r17: classic fp32-GEMM layer deleted; layer 3 also runs the MFMA path
// (r16 post-mortem: the classic l3 was the single largest dispatch at
// 160us vs ~90us for the MFMA layers; the fp32 hedge cost 70us). Error
// budget for fp16 GEMM at l3: sqrt(256) x 0.088 x 2^-11 x |x| ~ 1-2e-3 on
// top of 0.0039 -> expect absmax <= 0.0078.
// Per block D = Wcat x [agg|x]: M=128 feats, N=32 nodes, K=256,
// mfma_f32_16x16x32_f16, swapped operands so each lane ends with 4
// CONSECUTIVE features of one node. Weights fragment-prepacked fp16,
// preloaded to 16 VGPR-quads before the barrier (L2-hot, latency hides
// under the gather).
// INFMT: 0 = fp8 gather (8-lane groups, 32 concurrent nodes),
//        1 = fp16 gather (16-lane groups, 2 sequential nodes each).
// OUTFMT: 0 = fp8 shadow out, 1 = fp16 shadow out, 2 = none.
template<int INFMT, int OUTFMT>
__global__ __launch_bounds__(256, 4)
void sage_layer_mfma(const float* __restrict__ xin,
                     const void* __restrict__ xq_in,
                     float* __restrict__ xout,
                     void* __restrict__ xq_out,
                     const int* __restrict__ row_start, const int* __restrict__ csr,
                     const float* __restrict__ inv_deg,
                     const __half* __restrict__ wpack,
                     const float* __restrict__ bl, int n_nodes) {
    __shared__ __align__(16) __half Ah[TM][AHP];
    int block0 = blockIdx.x * TM;
    int tid = threadIdx.x;
    int lane = tid & 63;
    int wv   = tid >> 6;

    // X-fill: x (fp32, nt) -> fp16 into columns 128..255 of A-tile.
    {
        int row = tid >> 3;          // 0..31
        int seg = tid & 7;           // 16 halves per thread
        int nn = block0 + row;
        f4v v0 = {0,0,0,0}, v1 = v0, v2 = v0, v3 = v0;
        if (nn < n_nodes) {
            const f4v* xp = (const f4v*)(xin + (size_t)nn * D) + seg * 4;
            v0 = __builtin_nontemporal_load(xp);
            v1 = __builtin_nontemporal_load(xp + 1);
            v2 = __builtin_nontemporal_load(xp + 2);
            v3 = __builtin_nontemporal_load(xp + 3);
        }
        uint4 ua = {pkh(v0.x,v0.y), pkh(v0.z,v0.w), pkh(v1.x,v1.y), pkh(v1.z,v1.w)};
        uint4 ub = {pkh(v2.x,v2.y), pkh(v2.z,v2.w), pkh(v3.x,v3.y), pkh(v3.z,v3.w)};
        uint4* dst = (uint4*)&Ah[row][128 + seg * 16];
        dst[0] = ua; dst[1] = ub;
    }

    // Phase A: gather -> fp32 acc -> fp16 into columns 0..127 of A-tile.
    if constexpr (INFMT == 0) {
        // fp8: 8-lane group per node, 32 concurrent nodes, 4-deep pipeline.
        int g   = tid >> 3;       // 0..31
        int sub = tid & 7;
        int n = block0 + g;
        float4 s0 = {0,0,0,0}, s1 = {0,0,0,0}, s2 = {0,0,0,0}, s3 = {0,0,0,0};
        float idg = 1.f;
        int e0 = 0, e1 = 0;
        if (n < n_nodes) {
            e0 = row_start[n];
            e1 = row_start[n + 1];
            idg = inv_deg[n];
        }
        int e = e0;
        if (e < e1) {
            int last = e1 - 1;
            const char* qbase = (const char*)xq_in;
            int laneoff = sub * 16;
            int i0 = csr[min(e,     last)];
            int i1 = csr[min(e + 1, last)];
            int i2 = csr[min(e + 2, last)];
            int i3 = csr[min(e + 3, last)];
            while (1) {
                uint4 v0 = *(const uint4*)(qbase + (size_t)(i0 + laneoff));
                uint4 v1 = *(const uint4*)(qbase + (size_t)(i1 + laneoff));
                uint4 v2 = *(const uint4*)(qbase + (size_t)(i2 + laneoff));
                uint4 v3 = *(const uint4*)(qbase + (size_t)(i3 + laneoff));
                int en = e + 4;
                bool more = en < e1;
                int p0, p1, p2, p3;
                if (more) {
                    p0 = csr[min(en,     last)];
                    p1 = csr[min(en + 1, last)];
                    p2 = csr[min(en + 2, last)];
                    p3 = csr[min(en + 3, last)];
                }
                ACC16Q(v0)
                if (e + 1 <= last) ACC16Q(v1)
                if (e + 2 <= last) ACC16Q(v2)
                if (e + 3 <= last) ACC16Q(v3)
                if (!more) break;
                e = en;
                i0 = p0; i1 = p1; i2 = p2; i3 = p3;
            }
        }
        float sc = idg * Q8_INV;
        uint4 ua = {pkh(s0.x*sc,s0.y*sc), pkh(s0.z*sc,s0.w*sc),
                    pkh(s1.x*sc,s1.y*sc), pkh(s1.z*sc,s1.w*sc)};
        uint4 ub = {pkh(s2.x*sc,s2.y*sc), pkh(s2.z*sc,s2.w*sc),
                    pkh(s3.x*sc,s3.y*sc), pkh(s3.z*sc,s3.w*sc)};
        uint4* dst = (uint4*)&Ah[g][sub * 16];
        dst[0] = ua; dst[1] = ub;
    } else {
        // fp16: 16-lane group per node, 2 sequential nodes per group.
        int g   = tid >> 4;       // 0..15
        int sub = tid & 15;
        const char* hbase = (const char*)xq_in;
        int laneoff = sub * 16;   // 16B per lane within 256B fp16 row
        for (int t = 0; t < 2; ++t) {
            int j = g + t * 16;
            int n = block0 + j;
            float4 sA = {0,0,0,0}, sB = {0,0,0,0};
            float idg = 1.f;
            int e0 = 0, e1 = 0;
            if (n < n_nodes) {
                e0 = row_start[n];
                e1 = row_start[n + 1];
                idg = inv_deg[n];
            }
            int e = e0;
            if (e < e1) {
                int last = e1 - 1;
                int i0 = csr[min(e,     last)] << 1;
                int i1 = csr[min(e + 1, last)] << 1;
                int i2 = csr[min(e + 2, last)] << 1;
                int i3 = csr[min(e + 3, last)] << 1;
                while (1) {
                    float4 v0 = *(const float4*)(hbase + (size_t)(i0 + laneoff));
                    float4 v1 = *(const float4*)(hbase + (size_t)(i1 + laneoff));
                    float4 v2 = *(const float4*)(hbase + (size_t)(i2 + laneoff));
                    float4 v3 = *(const float4*)(hbase + (size_t)(i3 + laneoff));
                    int en = e + 4;
                    bool more = en < e1;
                    int p0, p1, p2, p3;
                    if (more) {
                        p0 = csr[min(en,     last)] << 1;
                        p1 = csr[min(en + 1, last)] << 1;
                        p2 = csr[min(en + 2, last)] << 1;
                        p3 = csr[min(en + 3, last)] << 1;
                    }
                    ACC8(v0)
                    if (e + 1 <= last) ACC8(v1)
                    if (e + 2 <= last) ACC8(v2)
                    if (e + 3 <= last) ACC8(v3)
                    if (!more) break;
                    e = en;
                    i0 = p0; i1 = p1; i2 = p2; i3 = p3;
                }
            }
            uint4 u = {pkh(sA.x*idg, sA.y*idg), pkh(sA.z*idg, sA.w*idg),
                       pkh(sB.x*idg, sB.y*idg), pkh(sB.z*idg, sB.w*idg)};
            *(uint4*)&Ah[j][sub * 8] = u;
        }
    }

    // Preload this wave's 16 weight fragments (2 f-tiles x 8 k-steps),
    // each a unique-data coalesced 1KB dwordx4. L2-hot after block 0.
    uint4 wf[16];
    {
        const uint4* wp = (const uint4*)wpack;
        #pragma unroll
        for (int i = 0; i < 16; ++i) {
            int ft = wv * 2 + (i >> 3);
            int ks = i & 7;
            wf[i] = wp[(size_t)(ft * 8 + ks) * 64 + lane];
        }
    }

    __syncthreads();

    // Phase B: wave wv owns feature tiles {2wv, 2wv+1} x node tiles {0,1}.
    {
        f4v acc[2][2];
        #pragma unroll
        for (int ft = 0; ft < 2; ++ft) {
            int f0 = wv * 32 + ft * 16 + ((lane >> 4) << 2);
            f4v bv = *(const f4v*)(bl + f0);
            acc[ft][0] = bv;
            acc[ft][1] = bv;
        }
        #pragma unroll
        for (int ks = 0; ks < 8; ++ks) {
            int koff = ks * 32 + ((lane >> 4) << 3);
            h8v b0 = *(const h8v*)&Ah[lane & 15][koff];
            h8v b1 = *(const h8v*)&Ah[16 + (lane & 15)][koff];
            h8v a0 = *(const h8v*)&wf[ks];
            h8v a1 = *(const h8v*)&wf[8 + ks];
            acc[0][0] = __builtin_amdgcn_mfma_f32_16x16x32_f16(a0, b0, acc[0][0], 0, 0, 0);
            acc[0][1] = __builtin_amdgcn_mfma_f32_16x16x32_f16(a0, b1, acc[0][1], 0, 0, 0);
            acc[1][0] = __builtin_amdgcn_mfma_f32_16x16x32_f16(a1, b0, acc[1][0], 0, 0, 0);
            acc[1][1] = __builtin_amdgcn_mfma_f32_16x16x32_f16(a1, b1, acc[1][1], 0, 0, 0);
        }
        // Epilogue: lane holds 4 consecutive feats of node (lane&15) per tile.
        #pragma unroll
        for (int ft = 0; ft < 2; ++ft) {
            #pragma unroll
            for (int nt = 0; nt < 2; ++nt) {
                int node = block0 + nt * 16 + (lane & 15);
                int f0 = wv * 32 + ft * 16 + ((lane >> 4) << 2);
                f4v r = acc[ft][nt];
                r.x = fmaxf(r.x, 0.f); r.y = fmaxf(r.y, 0.f);
                r.z = fmaxf(r.z, 0.f); r.w = fmaxf(r.w, 0.f);
                if (node < n_nodes) {
                    __builtin_nontemporal_store(r, (f4v*)(xout + (size_t)node * D + f0));
                    if constexpr (OUTFMT == 0) {
                        unsigned u = 0;
                        u = __builtin_amdgcn_cvt_pk_fp8_f32(r.x * Q8_SCALE, r.y * Q8_SCALE, u, false);
                        u = __builtin_amdgcn_cvt_pk_fp8_f32(r.z * Q8_SCALE, r.w * Q8_SCALE, u, true);
                        ((unsigned*)xq_out)[(size_t)node * 32 + (f0 >> 2)] = u;
                    } else if constexpr (OUTFMT == 1) {
                        uint2 u = {pkh(r.x, r.y), pkh(r.z, r.w)};
                        ((uint2*)xq_out)[(size_t)node * 32 + (f0 >> 2)] = u;
                    }
                }
            }
        }
    }
}

extern "C" void kernel_launch(void* const* d_in, const int* in_sizes, int n_in,
                              void* d_out, int out_size, void* d_ws, size_t ws_size,
                              hipStream_t stream) {
    const float* x  = (const float*)d_in[0];
    const int*  edge = (const int*)d_in[1];
    const float* Wl = (const float*)d_in[2];
    const float* bl = (const float*)d_in[3];
    const float* Wr = (const float*)d_in[4];

    int N = in_sizes[0] / D;
    int E = in_sizes[1] / 2;
    int L = in_sizes[3] / D;   // 4
    const int* srcp = edge;
    const int* dstp = edge + E;

    char* w = (char*)d_ws;
    auto alloc = [&](size_t bytes) {
        char* p = w;
        w += (bytes + 255) & ~(size_t)255;
        return p;
    };
    int*   deg       = (int*)alloc((size_t)N * 4);
    int*   local_ex  = (int*)alloc((size_t)N * 4);
    int*   row_start = (int*)alloc((size_t)(N + 1) * 4);
    int*   cursor    = (int*)alloc((size_t)N * 4);
    int*   csr       = (int*)alloc((size_t)E * 4);
    float* invdeg    = (float*)alloc((size_t)N * 4);
    int*   blocksum  = (int*)alloc((size_t)1024 * 4);
    __half* wpack    = (__half*)alloc((size_t)L * 32768 * 2);   // 64KB/layer
    float* buf0      = (float*)alloc((size_t)N * D * 4);
    unsigned* q0     = (unsigned*)alloc((size_t)N * D);         // fp8 rows
    void*  q1        = (void*)alloc((size_t)N * D * 2);         // fp8/fp16 rows

    int nb1 = (N + 1023) / 1024;
    hipMemsetAsync(deg, 0, (size_t)N * 4, stream);
    hist_kernel<<<(E + 255) / 256, 256, 0, stream>>>(dstp, deg, E);
    scan1_kernel<<<nb1, 1024, 0, stream>>>(deg, local_ex, blocksum, N);
    scan2_kernel<<<1, 1024, 0, stream>>>(blocksum, nb1);
    scan3_kernel<<<nb1, 1024, 0, stream>>>(deg, local_ex, blocksum, row_start,
                                           cursor, invdeg, N, E);
    scatter_kernel<<<(E + 255) / 256, 256, 0, stream>>>(srcp, dstp, cursor, csr, E);
    int tp = L * 4096;
    prepack_w<<<(tp + 255) / 256, 256, 0, stream>>>(Wl, Wr, wpack, tp);
    int t4 = N * (D / 4);
    x_to_fp8<<<(t4 + 255) / 256, 256, 0, stream>>>(x, q0, t4);

    float* out = (float*)d_out;
    int nbl = (N + TM - 1) / TM;

    // l0: gather fp8(x) -> fp8 shadow         fp32: x    -> buf0
    sage_layer_mfma<0, 0><<<nbl, 256, 0, stream>>>(x, q0, buf0, q1, row_start, csr, invdeg,
                                                   wpack + 0 * 32768, bl + 0 * D, N);
    // l1: gather fp8 -> fp8 shadow            fp32: buf0 -> out
    sage_layer_mfma<0, 0><<<nbl, 256, 0, stream>>>(buf0, q1, out, q0, row_start, csr, invdeg,
                                                   wpack + 1 * 32768, bl + 1 * D, N);
    // l2: gather fp8 -> FP16 shadow (hedge)   fp32: out  -> buf0
    sage_layer_mfma<0, 1><<<nbl, 256, 0, stream>>>(out, q0, buf0, q1, row_start, csr, invdeg,
                                                   wpack + 2 * 32768, bl + 2 * D, N);
    // l3: gather fp16 -> no shadow write      fp32: buf0 -> out (final)
    sage_layer_mfma<1, 2><<<nbl, 256, 0, stream>>>(buf0, q1, out, nullptr, row_start, csr, invdeg,
                                                   wpack + 3 * 32768, bl + 3 * D, N);
}

// Round 9
// 516.592 us; speedup vs baseline: 2.3047x; 1.0902x over previous
//
#include <hip/hip_runtime.h>
#include <hip/hip_fp16.h>

#define D 128
#define TM 32    // nodes per block
#define AHP 264  // MFMA A-tile halves/row: 528B, +16B pad -> <=2-way bank alias

typedef float f4v __attribute__((ext_vector_type(4)));
typedef float f2v __attribute__((ext_vector_type(2)));
typedef _Float16 h8v __attribute__((ext_vector_type(8)));

#define Q8_SCALE 16.0f      // fp8 storage scale: |act|*16 << 448 (e4m3 max)
#define Q8_INV   0.0625f

static __device__ __forceinline__ unsigned pkh(float a, float b) {
    __half2 h = __float22half2_rn(make_float2(a, b));
    return *(unsigned*)&h;
}

// ---------------- CSR build ----------------

__global__ void hist_kernel(const int* __restrict__ dst, int* __restrict__ deg, int E) {
    int i = blockIdx.x * blockDim.x + threadIdx.x;
    if (i < E) atomicAdd(&deg[dst[i]], 1);
}

__global__ void scan1_kernel(const int* __restrict__ deg, int* __restrict__ local_excl,
                             int* __restrict__ blocksum, int n) {
    __shared__ int tmp[1024];
    int i = blockIdx.x * 1024 + threadIdx.x;
    int v = (i < n) ? deg[i] : 0;
    tmp[threadIdx.x] = v;
    __syncthreads();
    for (int off = 1; off < 1024; off <<= 1) {
        int t = 0;
        if (threadIdx.x >= off) t = tmp[threadIdx.x - off];
        __syncthreads();
        if (threadIdx.x >= off) tmp[threadIdx.x] += t;
        __syncthreads();
    }
    int incl = tmp[threadIdx.x];
    if (i < n) local_excl[i] = incl - v;
    if (threadIdx.x == 1023) blocksum[blockIdx.x] = tmp[1023];
}

__global__ void scan2_kernel(int* __restrict__ blocksum, int nb) {
    __shared__ int tmp[1024];
    int v = (threadIdx.x < nb) ? blocksum[threadIdx.x] : 0;
    tmp[threadIdx.x] = v;
    __syncthreads();
    for (int off = 1; off < 1024; off <<= 1) {
        int t = 0;
        if (threadIdx.x >= off) t = tmp[threadIdx.x - off];
        __syncthreads();
        if (threadIdx.x >= off) tmp[threadIdx.x] += t;
        __syncthreads();
    }
    if (threadIdx.x < nb) blocksum[threadIdx.x] = tmp[threadIdx.x] - v;  // exclusive
}

__global__ void scan3_kernel(const int* __restrict__ deg, const int* __restrict__ local_excl,
                             const int* __restrict__ blocksum, int* __restrict__ row_start,
                             int* __restrict__ cursor, float* __restrict__ inv_deg,
                             int n, int n_edges) {
    int i = blockIdx.x * 1024 + threadIdx.x;
    if (i < n) {
        int rs = local_excl[i] + blocksum[blockIdx.x];
        row_start[i] = rs;
        cursor[i]    = rs;
        inv_deg[i]   = 1.0f / fmaxf((float)deg[i], 1.0f);
    }
    if (i == 0) row_start[n] = n_edges;
}

// csr[] holds BYTE offsets of the fp8 source row (src * 128).
// r18: XCD-affine scatter. r17 post-mortem: scatter was the largest
// dispatch (121us) with WRITE_SIZE=105MB ~= 1.6M x 64B -- every 4B csr
// store cost a full line writeback because the 8 private L2s each held a
// partial dirty copy of each line (~2 of 16 entries per XCD). Fix: XCD
// slot x = blockIdx&7 (round-robin dispatch heuristic) processes ONLY
// edges with dst in range x -> each csr line written by exactly one XCD
// -> L2 coalesces 16 entries -> writebacks ~6.4MB. Edge chunks are re-read
// by all 8 slots; re-reads are L3-served (FETCH counts HBM only).
// Correctness never depends on the %8 mapping.
__global__ void scatter_kernel(const int* __restrict__ src, const int* __restrict__ dst,
                               int* __restrict__ cursor, int* __restrict__ csr,
                               int E, int npx) {
    int x  = blockIdx.x & 7;
    int lo = x * npx, hi = lo + npx;
    int stride = (gridDim.x >> 3) * blockDim.x;
    for (int i = (blockIdx.x >> 3) * blockDim.x + threadIdx.x; i < E; i += stride) {
        int d = dst[i];
        if (d >= lo && d < hi) {
            int p = atomicAdd(&cursor[d], 1);
            csr[p] = src[i] << 7;
        }
    }
}

// ---------------- MFMA weight prepack ----------------
// Fragment-order fp16 pack for mfma_f32_16x16x32_f16, swapped-operand use:
// A-operand = weight tile, lane l holds row f = ft*16+(l&15),
// k = ks*32 + (l>>4)*8 + j (j=0..7). K-concat: ks 0..3 -> Wl (agg path),
// ks 4..7 -> Wr (x path). One thread emits one lane's 8 halves (16B), so a
// fragment = 64 consecutive uint4 = 1KB contiguous -> frag loads in the
// layer kernel are unique-data coalesced dwordx4.
__global__ void prepack_w(const float* __restrict__ Wl, const float* __restrict__ Wr,
                          __half* __restrict__ wpack, int total) {
    int t = blockIdx.x * blockDim.x + threadIdx.x;   // ((l*8+ft)*8+ks)*64+lane
    if (t >= total) return;
    int lane = t & 63;
    int ks   = (t >> 6) & 7;
    int ft   = (t >> 9) & 7;
    int l    = t >> 12;
    int f = ft * 16 + (lane & 15);
    int k = (ks & 3) * 32 + ((lane >> 4) << 3);
    const float* W = (ks < 4) ? Wl : Wr;
    const float* src = W + ((size_t)l << 14) + ((size_t)f << 7) + k;
    float4 v0 = *(const float4*)src;
    float4 v1 = *(const float4*)(src + 4);
    uint4 u = {pkh(v0.x, v0.y), pkh(v0.z, v0.w), pkh(v1.x, v1.y), pkh(v1.z, v1.w)};
    ((uint4*)wpack)[t] = u;
}

// ---------------- initial fp32 -> fp8(e4m3, x16) shadow copy ----------------

__global__ void x_to_fp8(const float* __restrict__ x, unsigned* __restrict__ xq, int total4) {
    int i = blockIdx.x * blockDim.x + threadIdx.x;
    if (i < total4) {
        float4 v = ((const float4*)x)[i];
        unsigned u = 0;
        u = __builtin_amdgcn_cvt_pk_fp8_f32(v.x * Q8_SCALE, v.y * Q8_SCALE, u, false);
        u = __builtin_amdgcn_cvt_pk_fp8_f32(v.z * Q8_SCALE, v.w * Q8_SCALE, u, true);
        xq[i] = u;
    }
}

// ---------------- gather helpers ----------------

#define ACC16Q(V) {                                                          \
    f2v a0_ = __builtin_amdgcn_cvt_pk_f32_fp8((int)(V).x, false);            \
    f2v a1_ = __builtin_amdgcn_cvt_pk_f32_fp8((int)(V).x, true);             \
    f2v b0_ = __builtin_amdgcn_cvt_pk_f32_fp8((int)(V).y, false);            \
    f2v b1_ = __builtin_amdgcn_cvt_pk_f32_fp8((int)(V).y, true);             \
    f2v c0_ = __builtin_amdgcn_cvt_pk_f32_fp8((int)(V).z, false);            \
    f2v c1_ = __builtin_amdgcn_cvt_pk_f32_fp8((int)(V).z, true);             \
    f2v d0_ = __builtin_amdgcn_cvt_pk_f32_fp8((int)(V).w, false);            \
    f2v d1_ = __builtin_amdgcn_cvt_pk_f32_fp8((int)(V).w, true);             \
    s0.x += a0_.x; s0.y += a0_.y; s0.z += a1_.x; s0.w += a1_.y;              \
    s1.x += b0_.x; s1.y += b0_.y; s1.z += b1_.x; s1.w += b1_.y;              \
    s2.x += c0_.x; s2.y += c0_.y; s2.z += c1_.x; s2.w += c1_.y;              \
    s3.x += d0_.x; s3.y += d0_.y; s3.z += d1_.x; s3.w += d1_.y; }

#define ACC8(V) { const __half2* hp_ = (const __half2*)&(V);                 \
    float2 f0_ = __half22float2(hp_[0]); float2 f1_ = __half22float2(hp_[1]);\
    float2 f2_ = __half22float2(hp_[2]); float2 f3_ = __half22float2(hp_[3]);\
    sA.x += f0_.x; sA.y += f0_.y; sA.z += f1_.x; sA.w += f1_.y;              \
    sB.x += f2_.x; sB.y += f2_.y; sB.z += f3_.x; sB.w += f3_.y; }

// ---------------- MFMA fused SAGE layer ----------------
// Per block D = Wcat x [agg|x]: M=128 feats, N=32 nodes, K=256,
// mfma_f32_16x16x32_f16, swapped operands so each lane ends with 4
// CONSECUTIVE features of one node. Weights fragment-prepacked fp16,
// preloaded to 16 VGPR-quads before the barrier (L2-hot, latency hides
// under the gather).
// INFMT: 0 = fp8 gather (8-lane groups, 32 concurrent nodes),
//        1 = fp16 gather (16-lane groups, 2 sequential nodes each).
// OUTFMT: 0 = fp8 shadow out, 1 = fp16 shadow out, 2 = none.
template<int INFMT, int OUTFMT>
__global__ __launch_bounds__(256, 4)
void sage_layer_mfma(const float* __restrict__ xin,
                     const void* __restrict__ xq_in,
                     float* __restrict__ xout,
                     void* __restrict__ xq_out,
                     const int* __restrict__ row_start, const int* __restrict__ csr,
                     const float* __restrict__ inv_deg,
                     const __half* __restrict__ wpack,
                     const float* __restrict__ bl, int n_nodes) {
    __shared__ __align__(16) __half Ah[TM][AHP];
    int block0 = blockIdx.x * TM;
    int tid = threadIdx.x;
    int lane = tid & 63;
    int wv   = tid >> 6;

    // X-fill: x (fp32, nt) -> fp16 into columns 128..255 of A-tile.
    {
        int row = tid >> 3;          // 0..31
        int seg = tid & 7;           // 16 halves per thread
        int nn = block0 + row;
        f4v v0 = {0,0,0,0}, v1 = v0, v2 = v0, v3 = v0;
        if (nn < n_nodes) {
            const f4v* xp = (const f4v*)(xin + (size_t)nn * D) + seg * 4;
            v0 = __builtin_nontemporal_load(xp);
            v1 = __builtin_nontemporal_load(xp + 1);
            v2 = __builtin_nontemporal_load(xp + 2);
            v3 = __builtin_nontemporal_load(xp + 3);
        }
        uint4 ua = {pkh(v0.x,v0.y), pkh(v0.z,v0.w), pkh(v1.x,v1.y), pkh(v1.z,v1.w)};
        uint4 ub = {pkh(v2.x,v2.y), pkh(v2.z,v2.w), pkh(v3.x,v3.y), pkh(v3.z,v3.w)};
        uint4* dst = (uint4*)&Ah[row][128 + seg * 16];
        dst[0] = ua; dst[1] = ub;
    }

    // Phase A: gather -> fp32 acc -> fp16 into columns 0..127 of A-tile.
    if constexpr (INFMT == 0) {
        // fp8: 8-lane group per node, 32 concurrent nodes, 4-deep pipeline.
        int g   = tid >> 3;       // 0..31
        int sub = tid & 7;
        int n = block0 + g;
        float4 s0 = {0,0,0,0}, s1 = {0,0,0,0}, s2 = {0,0,0,0}, s3 = {0,0,0,0};
        float idg = 1.f;
        int e0 = 0, e1 = 0;
        if (n < n_nodes) {
            e0 = row_start[n];
            e1 = row_start[n + 1];
            idg = inv_deg[n];
        }
        int e = e0;
        if (e < e1) {
            int last = e1 - 1;
            const char* qbase = (const char*)xq_in;
            int laneoff = sub * 16;
            int i0 = csr[min(e,     last)];
            int i1 = csr[min(e + 1, last)];
            int i2 = csr[min(e + 2, last)];
            int i3 = csr[min(e + 3, last)];
            while (1) {
                uint4 v0 = *(const uint4*)(qbase + (size_t)(i0 + laneoff));
                uint4 v1 = *(const uint4*)(qbase + (size_t)(i1 + laneoff));
                uint4 v2 = *(const uint4*)(qbase + (size_t)(i2 + laneoff));
                uint4 v3 = *(const uint4*)(qbase + (size_t)(i3 + laneoff));
                int en = e + 4;
                bool more = en < e1;
                int p0, p1, p2, p3;
                if (more) {
                    p0 = csr[min(en,     last)];
                    p1 = csr[min(en + 1, last)];
                    p2 = csr[min(en + 2, last)];
                    p3 = csr[min(en + 3, last)];
                }
                ACC16Q(v0)
                if (e + 1 <= last) ACC16Q(v1)
                if (e + 2 <= last) ACC16Q(v2)
                if (e + 3 <= last) ACC16Q(v3)
                if (!more) break;
                e = en;
                i0 = p0; i1 = p1; i2 = p2; i3 = p3;
            }
        }
        float sc = idg * Q8_INV;
        uint4 ua = {pkh(s0.x*sc,s0.y*sc), pkh(s0.z*sc,s0.w*sc),
                    pkh(s1.x*sc,s1.y*sc), pkh(s1.z*sc,s1.w*sc)};
        uint4 ub = {pkh(s2.x*sc,s2.y*sc), pkh(s2.z*sc,s2.w*sc),
                    pkh(s3.x*sc,s3.y*sc), pkh(s3.z*sc,s3.w*sc)};
        uint4* dst = (uint4*)&Ah[g][sub * 16];
        dst[0] = ua; dst[1] = ub;
    } else {
        // fp16: 16-lane group per node, 2 sequential nodes per group.
        int g   = tid >> 4;       // 0..15
        int sub = tid & 15;
        const char* hbase = (const char*)xq_in;
        int laneoff = sub * 16;   // 16B per lane within 256B fp16 row
        for (int t = 0; t < 2; ++t) {
            int j = g + t * 16;
            int n = block0 + j;
            float4 sA = {0,0,0,0}, sB = {0,0,0,0};
            float idg = 1.f;
            int e0 = 0, e1 = 0;
            if (n < n_nodes) {
                e0 = row_start[n];
                e1 = row_start[n + 1];
                idg = inv_deg[n];
            }
            int e = e0;
            if (e < e1) {
                int last = e1 - 1;
                int i0 = csr[min(e,     last)] << 1;
                int i1 = csr[min(e + 1, last)] << 1;
                int i2 = csr[min(e + 2, last)] << 1;
                int i3 = csr[min(e + 3, last)] << 1;
                while (1) {
                    float4 v0 = *(const float4*)(hbase + (size_t)(i0 + laneoff));
                    float4 v1 = *(const float4*)(hbase + (size_t)(i1 + laneoff));
                    float4 v2 = *(const float4*)(hbase + (size_t)(i2 + laneoff));
                    float4 v3 = *(const float4*)(hbase + (size_t)(i3 + laneoff));
                    int en = e + 4;
                    bool more = en < e1;
                    int p0, p1, p2, p3;
                    if (more) {
                        p0 = csr[min(en,     last)] << 1;
                        p1 = csr[min(en + 1, last)] << 1;
                        p2 = csr[min(en + 2, last)] << 1;
                        p3 = csr[min(en + 3, last)] << 1;
                    }
                    ACC8(v0)
                    if (e + 1 <= last) ACC8(v1)
                    if (e + 2 <= last) ACC8(v2)
                    if (e + 3 <= last) ACC8(v3)
                    if (!more) break;
                    e = en;
                    i0 = p0; i1 = p1; i2 = p2; i3 = p3;
                }
            }
            uint4 u = {pkh(sA.x*idg, sA.y*idg), pkh(sA.z*idg, sA.w*idg),
                       pkh(sB.x*idg, sB.y*idg), pkh(sB.z*idg, sB.w*idg)};
            *(uint4*)&Ah[j][sub * 8] = u;
        }
    }

    // Preload this wave's 16 weight fragments (2 f-tiles x 8 k-steps),
    // each a unique-data coalesced 1KB dwordx4. L2-hot after block 0.
    uint4 wf[16];
    {
        const uint4* wp = (const uint4*)wpack;
        #pragma unroll
        for (int i = 0; i < 16; ++i) {
            int ft = wv * 2 + (i >> 3);
            int ks = i & 7;
            wf[i] = wp[(size_t)(ft * 8 + ks) * 64 + lane];
        }
    }

    __syncthreads();

    // Phase B: wave wv owns feature tiles {2wv, 2wv+1} x node tiles {0,1}.
    {
        f4v acc[2][2];
        #pragma unroll
        for (int ft = 0; ft < 2; ++ft) {
            int f0 = wv * 32 + ft * 16 + ((lane >> 4) << 2);
            f4v bv = *(const f4v*)(bl + f0);
            acc[ft][0] = bv;
            acc[ft][1] = bv;
        }
        #pragma unroll
        for (int ks = 0; ks < 8; ++ks) {
            int koff = ks * 32 + ((lane >> 4) << 3);
            h8v b0 = *(const h8v*)&Ah[lane & 15][koff];
            h8v b1 = *(const h8v*)&Ah[16 + (lane & 15)][koff];
            h8v a0 = *(const h8v*)&wf[ks];
            h8v a1 = *(const h8v*)&wf[8 + ks];
            acc[0][0] = __builtin_amdgcn_mfma_f32_16x16x32_f16(a0, b0, acc[0][0], 0, 0, 0);
            acc[0][1] = __builtin_amdgcn_mfma_f32_16x16x32_f16(a0, b1, acc[0][1], 0, 0, 0);
            acc[1][0] = __builtin_amdgcn_mfma_f32_16x16x32_f16(a1, b0, acc[1][0], 0, 0, 0);
            acc[1][1] = __builtin_amdgcn_mfma_f32_16x16x32_f16(a1, b1, acc[1][1], 0, 0, 0);
        }
        // Epilogue: lane holds 4 consecutive feats of node (lane&15) per tile.
        #pragma unroll
        for (int ft = 0; ft < 2; ++ft) {
            #pragma unroll
            for (int nt = 0; nt < 2; ++nt) {
                int node = block0 + nt * 16 + (lane & 15);
                int f0 = wv * 32 + ft * 16 + ((lane >> 4) << 2);
                f4v r = acc[ft][nt];
                r.x = fmaxf(r.x, 0.f); r.y = fmaxf(r.y, 0.f);
                r.z = fmaxf(r.z, 0.f); r.w = fmaxf(r.w, 0.f);
                if (node < n_nodes) {
                    __builtin_nontemporal_store(r, (f4v*)(xout + (size_t)node * D + f0));
                    if constexpr (OUTFMT == 0) {
                        unsigned u = 0;
                        u = __builtin_amdgcn_cvt_pk_fp8_f32(r.x * Q8_SCALE, r.y * Q8_SCALE, u, false);
                        u = __builtin_amdgcn_cvt_pk_fp8_f32(r.z * Q8_SCALE, r.w * Q8_SCALE, u, true);
                        ((unsigned*)xq_out)[(size_t)node * 32 + (f0 >> 2)] = u;
                    } else if constexpr (OUTFMT == 1) {
                        uint2 u = {pkh(r.x, r.y), pkh(r.z, r.w)};
                        ((uint2*)xq_out)[(size_t)node * 32 + (f0 >> 2)] = u;
                    }
                }
            }
        }
    }
}

extern "C" void kernel_launch(void* const* d_in, const int* in_sizes, int n_in,
                              void* d_out, int out_size, void* d_ws, size_t ws_size,
                              hipStream_t stream) {
    const float* x  = (const float*)d_in[0];
    const int*  edge = (const int*)d_in[1];
    const float* Wl = (const float*)d_in[2];
    const float* bl = (const float*)d_in[3];
    const float* Wr = (const float*)d_in[4];

    int N = in_sizes[0] / D;
    int E = in_sizes[1] / 2;
    int L = in_sizes[3] / D;   // 4
    const int* srcp = edge;
    const int* dstp = edge + E;

    char* w = (char*)d_ws;
    auto alloc = [&](size_t bytes) {
        char* p = w;
        w += (bytes + 255) & ~(size_t)255;
        return p;
    };
    int*   deg       = (int*)alloc((size_t)N * 4);
    int*   local_ex  = (int*)alloc((size_t)N * 4);
    int*   row_start = (int*)alloc((size_t)(N + 1) * 4);
    int*   cursor    = (int*)alloc((size_t)N * 4);
    int*   csr       = (int*)alloc((size_t)E * 4);
    float* invdeg    = (float*)alloc((size_t)N * 4);
    int*   blocksum  = (int*)alloc((size_t)1024 * 4);
    __half* wpack    = (__half*)alloc((size_t)L * 32768 * 2);   // 64KB/layer
    float* buf0      = (float*)alloc((size_t)N * D * 4);
    unsigned* q0     = (unsigned*)alloc((size_t)N * D);         // fp8 rows
    void*  q1        = (void*)alloc((size_t)N * D * 2);         // fp8/fp16 rows

    int nb1 = (N + 1023) / 1024;
    hipMemsetAsync(deg, 0, (size_t)N * 4, stream);
    hist_kernel<<<(E + 255) / 256, 256, 0, stream>>>(dstp, deg, E);
    scan1_kernel<<<nb1, 1024, 0, stream>>>(deg, local_ex, blocksum, N);
    scan2_kernel<<<1, 1024, 0, stream>>>(blocksum, nb1);
    scan3_kernel<<<nb1, 1024, 0, stream>>>(deg, local_ex, blocksum, row_start,
                                           cursor, invdeg, N, E);
    int npx = (N + 7) / 8;
    scatter_kernel<<<2048, 256, 0, stream>>>(srcp, dstp, cursor, csr, E, npx);
    int tp = L * 4096;
    prepack_w<<<(tp + 255) / 256, 256, 0, stream>>>(Wl, Wr, wpack, tp);
    int t4 = N * (D / 4);
    x_to_fp8<<<(t4 + 255) / 256, 256, 0, stream>>>(x, q0, t4);

    float* out = (float*)d_out;
    int nbl = (N + TM - 1) / TM;

    // l0: gather fp8(x) -> fp8 shadow         fp32: x    -> buf0
    sage_layer_mfma<0, 0><<<nbl, 256, 0, stream>>>(x, q0, buf0, q1, row_start, csr, invdeg,
                                                   wpack + 0 * 32768, bl + 0 * D, N);
    // l1: gather fp8 -> fp8 shadow            fp32: buf0 -> out
    sage_layer_mfma<0, 0><<<nbl, 256, 0, stream>>>(buf0, q1, out, q0, row_start, csr, invdeg,
                                                   wpack + 1 * 32768, bl + 1 * D, N);
    // l2: gather fp8 -> FP16 shadow (hedge)   fp32: out  -> buf0
    sage_layer_mfma<0, 1><<<nbl, 256, 0, stream>>>(out, q0, buf0, q1, row_start, csr, invdeg,
                                                   wpack + 2 * 32768, bl + 2 * D, N);
    // l3: gather fp16 -> no shadow write      fp32: buf0 -> out (final)
    sage_layer_mfma<1, 2><<<nbl, 256, 0, stream>>>(buf0, q1, out, nullptr, row_start, csr, invdeg,
                                                   wpack + 3 * 32768, bl + 3 * D, N);
}